// Round 5
// baseline (11965.384 us; speedup 1.0000x reference)
//
#include <hip/hip_runtime.h>
#include <stdint.h>

typedef __attribute__((ext_vector_type(8))) short short8;
typedef __attribute__((ext_vector_type(4))) float f32x4;

#define MFMA16(a, b, c) __builtin_amdgcn_mfma_f32_16x16x32_bf16((a), (b), (c), 0, 0, 0)
#define AL(p) __hip_atomic_load((p), __ATOMIC_RELAXED, __HIP_MEMORY_SCOPE_AGENT)
#define AS(p, v) __hip_atomic_store((p), (v), __ATOMIC_RELAXED, __HIP_MEMORY_SCOPE_AGENT)

__device__ __forceinline__ unsigned short f2bf(float f) {
  unsigned u = __float_as_uint(f);
  u = (u + 0x7FFFu + ((u >> 16) & 1u)) >> 16;   // RNE
  return (unsigned short)u;
}
__device__ __forceinline__ float bf2f(unsigned short u) {
  return __uint_as_float(((unsigned)u) << 16);
}

// ---------------- prep: fp32 -> bf16 conversion ----------------
__global__ void k_cvt(const float* __restrict__ src, unsigned short* __restrict__ dst, int n4) {
  int stride = gridDim.x * blockDim.x;
  for (int i = blockIdx.x * blockDim.x + threadIdx.x; i < n4; i += stride) {
    float4 v = reinterpret_cast<const float4*>(src)[i];
    ushort4 o;
    o.x = f2bf(v.x); o.y = f2bf(v.y); o.z = f2bf(v.z); o.w = f2bf(v.w);
    reinterpret_cast<ushort4*>(dst)[i] = o;
  }
}

__global__ void k_bias(const float* __restrict__ a, const float* __restrict__ b,
                       float* __restrict__ o, int n) {
  int i = blockIdx.x * blockDim.x + threadIdx.x;
  if (i < n) o[i] = a[i] + b[i];
}

// ---------------- xp GEMM: writes per-column interleaved xp layout ----------------
// out element for (row r, gate col c): r*4096 + jc*4 + gate   (jc = c&1023, gate = c>>10)
__global__ __launch_bounds__(256) void k_gemm(
    const unsigned short* __restrict__ A,
    const unsigned short* __restrict__ W,
    const float* __restrict__ bias,
    unsigned short* __restrict__ out,
    int mode) {
  const int tid = threadIdx.x, l = tid & 63, wv = tid >> 6;
  const int wm = wv >> 1, wn = wv & 1;
  const int tm = blockIdx.x >> 5, tn = blockIdx.x & 31;   // 256 x 32 tiles of 128x128
  const int m_base = tm * 128 + wm * 64;
  const int n_base = tn * 128 + wn * 64;
  const int lr = l & 15, k8 = (l >> 4) << 3;

  size_t a_off[4], b_off[4];
#pragma unroll
  for (int i = 0; i < 4; ++i) {
    int r = m_base + i * 16 + lr;
    int ar = mode ? r : (((r & 63) << 9) + (r >> 6));
    a_off[i] = ((size_t)ar << 10) + k8;
    int nr = n_base + i * 16 + lr;
    b_off[i] = ((size_t)nr << 10) + k8;
  }
  f32x4 acc[4][4] = {};
#pragma unroll 2
  for (int k0 = 0; k0 < 1024; k0 += 32) {
    short8 a[4], b[4];
#pragma unroll
    for (int i = 0; i < 4; ++i) a[i] = *reinterpret_cast<const short8*>(A + a_off[i] + k0);
#pragma unroll
    for (int j = 0; j < 4; ++j) b[j] = *reinterpret_cast<const short8*>(W + b_off[j] + k0);
#pragma unroll
    for (int i = 0; i < 4; ++i)
#pragma unroll
      for (int j = 0; j < 4; ++j) acc[i][j] = MFMA16(a[i], b[j], acc[i][j]);
  }
  const int oq = (l >> 4) << 2, oc = l & 15;
#pragma unroll
  for (int j = 0; j < 4; ++j) {
    int col = n_base + j * 16 + oc;
    int gate = col >> 10, jc = col & 1023;
    size_t cidx = (size_t)((jc << 2) + gate);
    float bs = bias[col];
#pragma unroll
    for (int i = 0; i < 4; ++i) {
      int r0 = m_base + i * 16 + oq;
#pragma unroll
      for (int q = 0; q < 4; ++q)
        out[(((size_t)(r0 + q)) << 12) + cidx] = f2bf(acc[i][j][q] + bs);
    }
  }
}

// ---------------- persistent LSTM recurrence ----------------
// grid = 64 WGs x 1024 threads. Group g = wg>>4: batches [16g, 16g+16).
// WG w (0..15) owns h-cols [64w, 64w+64) -> 256 gate cols.
// Waves: wv = ks*4 + nt  (ks = K-quarter 0..3, nt = gate 0..3).
// W_hh frags register-resident (128 VGPR/thread). h staged once per WG into
// XOR-swizzled LDS (32 KB) -> 2 MB/step chip-wide broadcast (reg-W floor).
// Split-K partials via padded LDS (b-stride 266 words -> <=2-way banks).
__global__ __launch_bounds__(1024, 1) void k_rec(
    const unsigned short* __restrict__ xp,     // col-interleaved (S*B, 4096) bf16
    const unsigned short* __restrict__ Whh,    // (4096, 1024) bf16
    unsigned short* __restrict__ hbuf,         // 2 x (64 x 1024) bf16
    int* __restrict__ flags,                   // per group at +g*256: 16 flags
    unsigned short* __restrict__ out_bf,       // layer0: (S,B,1024) bf16, else null
    float* __restrict__ out_f32,               // layer1: (B,S,1024) fp32, else null
    float* __restrict__ hn, float* __restrict__ cn) {
  extern __shared__ char smem[];               // [0,32K) h swizzled; [32K,+68096) partials
  float* part = (float*)(smem + 32768);        // [(ks*16+b)*266 + tile*16 + c]

  const int tid = threadIdx.x;
  const int l = tid & 63, wv = tid >> 6;
  const int g = blockIdx.x >> 4;
  const int w = blockIdx.x & 15;
  const int hc0 = w << 6;

  int* gflags = flags + (g << 8);

  const int ks = wv >> 2, nt = wv & 3;
  const int lr16 = l & 15, k8 = (l >> 4) << 3;

  // ---- W_hh fragments -> registers (once): bf[jj][kk]
  // gate col = nt*1024 + hc0 + jj*16 + lr16 ; K = ks*256 + kk*32 + k8
  short8 bf[4][8];
#pragma unroll
  for (int jj = 0; jj < 4; ++jj) {
    const unsigned short* wp =
        Whh + ((size_t)((nt << 10) + hc0 + (jj << 4) + lr16) << 10) + (ks << 8) + k8;
#pragma unroll
    for (int kk = 0; kk < 8; ++kk)
      bf[jj][kk] = *reinterpret_cast<const short8*>(wp + (kk << 5));
  }

  // h staging: 2048 chunks of 16B; thread stages chunks tid and tid+1024.
  // chunk cid: row = cid>>7 (batch-in-group), c16 = cid&127.
  // LDS byte = row*2048 + ((c16 ^ (row&7))<<4); global = row row-major linear.
  const int r0c = tid >> 7, c0c = tid & 127;
  const int r1c = (tid + 1024) >> 7, c1c = tid & 127;   // (tid+1024)&127 == tid&127
  const int lds0 = (r0c << 11) + (((c0c ^ (r0c & 7)) & 127) << 4);
  const int lds1 = (r1c << 11) + (((c1c ^ (r1c & 7)) & 127) << 4);
  const size_t gsrc0 = ((size_t)r0c << 10) + (c0c << 3);   // ushorts
  const size_t gsrc1 = ((size_t)r1c << 10) + (c1c << 3);
  const unsigned short* hgb = hbuf + ((size_t)g << 14);    // group base (+ (t&1)<<16)

  // elementwise mapping: wave = batch, lane = h-col
  const int b_l = wv;
  const int j = l;
  const int b_g = (g << 4) + b_l;
  const int hcol = hc0 + j;

  float cs = 0.f;

  auto xload = [&](int t) -> uint2 {
    return *reinterpret_cast<const uint2*>(
        xp + (((size_t)((t << 6) + b_g)) << 12) + (hcol << 2));
  };

  auto step = [&](int t, uint2 xv) {
    if (t > 0) {
      // ---- stage h[t] (group's 16 rows x 1024 cols bf16) into swizzled LDS
      const unsigned short* hs = hgb + ((size_t)(t & 1) << 16);
      short8 h0, h1;
      {
        const unsigned short* p0 = hs + gsrc0;
        const unsigned short* p1 = hs + gsrc1;
        asm volatile("global_load_dwordx4 %0, %1, off sc0 sc1"
                     : "=v"(h0) : "v"(p0) : "memory");
        asm volatile("global_load_dwordx4 %0, %1, off sc0 sc1"
                     : "=v"(h1) : "v"(p1) : "memory");
      }
      asm volatile("s_waitcnt vmcnt(0)" ::: "memory");
      __builtin_amdgcn_sched_barrier(0);
      *reinterpret_cast<short8*>(smem + lds0) = h0;
      *reinterpret_cast<short8*>(smem + lds1) = h1;
    }
    __syncthreads();

    if (t > 0) {
      f32x4 acc[4] = {{0.f,0.f,0.f,0.f},{0.f,0.f,0.f,0.f},{0.f,0.f,0.f,0.f},{0.f,0.f,0.f,0.f}};
#pragma unroll
      for (int kk = 0; kk < 8; ++kk) {
        int ch = (ks << 5) + (kk << 2) + (l >> 4);
        short8 a = *reinterpret_cast<const short8*>(
            smem + (lr16 << 11) + ((ch ^ (lr16 & 7)) << 4));
#pragma unroll
        for (int jj = 0; jj < 4; ++jj) acc[jj] = MFMA16(a, bf[jj][kk], acc[jj]);
      }
      // D: row=(l>>4)*4+q (batch), col=lr16 (c within tile)
#pragma unroll
      for (int jj = 0; jj < 4; ++jj)
#pragma unroll
        for (int q = 0; q < 4; ++q) {
          int bq = ((l >> 4) << 2) + q;
          part[((ks << 4) + bq) * 266 + ((nt << 2) + jj) * 16 + lr16] = acc[jj][q];
        }
    }
    __syncthreads();

    // ---- elementwise: one (batch, hcol) per thread
    {
      float gi = bf2f((unsigned short)(xv.x)), gf = bf2f((unsigned short)(xv.x >> 16));
      float gg = bf2f((unsigned short)(xv.y)), go = bf2f((unsigned short)(xv.y >> 16));
      if (t > 0) {
        float si = 0.f, sf = 0.f, sg = 0.f, so = 0.f;
        const int eb = ((j >> 4) << 4) + (j & 15);   // tile-local offset
#pragma unroll
        for (int ksx = 0; ksx < 4; ++ksx) {
          const float* p = part + ((ksx << 4) + b_l) * 266 + eb;
          si += p[0];    // nt=0 (i)
          sf += p[64];   // nt=1 (f)
          sg += p[128];  // nt=2 (g)
          so += p[192];  // nt=3 (o)
        }
        gi += si; gf += sf; gg += sg; go += so;
      }
      float iv = 1.f / (1.f + __expf(-gi));
      float fv = 1.f / (1.f + __expf(-gf));
      float gv = tanhf(gg);
      float ov = 1.f / (1.f + __expf(-go));
      cs = fv * cs + iv * gv;
      float hv = ov * tanhf(cs);
      unsigned short h16 = f2bf(hv);

      AS(hbuf + ((size_t)((t + 1) & 1) << 16) + ((size_t)b_g << 10) + hcol, h16);
      if (out_bf) {
        out_bf[((((size_t)t << 6) + b_g) << 10) + hcol] = h16;
      } else {
        out_f32[((((size_t)b_g << 9) + t) << 10) + hcol] = hv;
      }
      if (t == 511) {
        hn[((size_t)b_g << 10) + hcol] = hv;
        cn[((size_t)b_g << 10) + hcol] = cs;
      }
    }

    // ---- group barrier: drain own h stores, arrive, wave0 polls 16 flags ----
    if (t != 511) {
      asm volatile("s_waitcnt vmcnt(0)" ::: "memory");
      __syncthreads();
      if (tid == 0) AS(&gflags[w], t + 1);
      if (wv == 0) {
        for (;;) {
          int f = AL(&gflags[l & 15]);
          if (__all(f > t)) break;
          __builtin_amdgcn_s_sleep(1);
        }
      }
      __syncthreads();
    }
  };

  // ---- main loop: 8-step superchunks, xp double-buffer prefetch ----
  uint2 zz = {0u, 0u};
  uint2 xA[4] = {zz, zz, zz, zz}, xB[4] = {zz, zz, zz, zz};
#pragma unroll
  for (int s = 0; s < 4; ++s) xA[s] = xload(s);
  for (int tc = 0; tc < 512; tc += 8) {
#pragma unroll
    for (int s = 0; s < 4; ++s) xB[s] = xload(tc + 4 + s);
#pragma unroll
    for (int s = 0; s < 4; ++s) step(tc + s, xA[s]);
    if (tc + 8 < 512) {
#pragma unroll
      for (int s = 0; s < 4; ++s) xA[s] = xload(tc + 8 + s);
    }
#pragma unroll
    for (int s = 0; s < 4; ++s) step(tc + 4 + s, xB[s]);
  }
}

// ---------------- launch ----------------
extern "C" void kernel_launch(void* const* d_in, const int* in_sizes, int n_in,
                              void* d_out, int out_size, void* d_ws, size_t ws_size,
                              hipStream_t stream) {
  (void)in_sizes; (void)n_in; (void)out_size; (void)ws_size;
  const float* x    = (const float*)d_in[0];
  const float* Wih0 = (const float*)d_in[1];
  const float* bih0 = (const float*)d_in[2];
  const float* Whh0 = (const float*)d_in[3];
  const float* bhh0 = (const float*)d_in[4];
  const float* Wih1 = (const float*)d_in[5];
  const float* bih1 = (const float*)d_in[6];
  const float* Whh1 = (const float*)d_in[7];
  const float* bhh1 = (const float*)d_in[8];
  float* dout = (float*)d_out;

  char* ws = (char*)d_ws;
  int*            flags = (int*)ws;                          // 8 KB
  unsigned short* hbuf  = (unsigned short*)(ws + 8192);      // 256 KB
  float*          bias0 = (float*)(ws + 270336);             // 16 KB
  float*          bias1 = (float*)(ws + 286720);             // 16 KB
  unsigned short* wbf   = (unsigned short*)(ws + 303104);    // 32 MB: ih0,hh0,ih1,hh1
  unsigned short* xbf   = wbf + 16777216;                    // 64 MB
  unsigned short* out0  = xbf + 33554432;                    // 64 MB
  unsigned short* xpb   = out0 + 33554432;                   // 256 MB (shared both layers)

  hipMemsetAsync(flags, 0, 8192, stream);

  k_cvt<<<1024, 256, 0, stream>>>(x, xbf, 33554432 / 4);
  k_cvt<<<256, 256, 0, stream>>>(Wih0, wbf + 0,        4194304 / 4);
  k_cvt<<<256, 256, 0, stream>>>(Whh0, wbf + 4194304,  4194304 / 4);
  k_cvt<<<256, 256, 0, stream>>>(Wih1, wbf + 8388608,  4194304 / 4);
  k_cvt<<<256, 256, 0, stream>>>(Whh1, wbf + 12582912, 4194304 / 4);
  k_bias<<<16, 256, 0, stream>>>(bih0, bhh0, bias0, 4096);
  k_bias<<<16, 256, 0, stream>>>(bih1, bhh1, bias1, 4096);

  hipFuncSetAttribute((const void*)k_rec,
                      hipFuncAttributeMaxDynamicSharedMemorySize, 100864);

  float* hn = dout + 33554432;
  float* cn = dout + 33554432 + 131072;

  // layer 0
  k_gemm<<<8192, 256, 0, stream>>>(xbf, wbf + 0, bias0, xpb, 0);
  k_rec<<<64, 1024, 100864, stream>>>(xpb, wbf + 4194304, hbuf, flags,
                                      out0, nullptr, hn, cn);
  // layer 1
  k_gemm<<<8192, 256, 0, stream>>>(out0, wbf + 8388608, bias1, xpb, 1);
  k_rec<<<64, 1024, 100864, stream>>>(xpb, wbf + 12582912, hbuf, flags + 1024,
                                      nullptr, dout, hn + 65536, cn + 65536);
}

// Round 6
// 6123.131 us; speedup vs baseline: 1.9541x; 1.9541x over previous
//
#include <hip/hip_runtime.h>
#include <stdint.h>

typedef __attribute__((ext_vector_type(8))) short short8;
typedef __attribute__((ext_vector_type(4))) float f32x4;

#define MFMA16(a, b, c) __builtin_amdgcn_mfma_f32_16x16x32_bf16((a), (b), (c), 0, 0, 0)
#define AL(p) __hip_atomic_load((p), __ATOMIC_RELAXED, __HIP_MEMORY_SCOPE_AGENT)
#define AS(p, v) __hip_atomic_store((p), (v), __ATOMIC_RELAXED, __HIP_MEMORY_SCOPE_AGENT)

__device__ __forceinline__ unsigned short f2bf(float f) {
  unsigned u = __float_as_uint(f);
  u = (u + 0x7FFFu + ((u >> 16) & 1u)) >> 16;   // RNE
  return (unsigned short)u;
}
__device__ __forceinline__ float bf2f(unsigned short u) {
  return __uint_as_float(((unsigned)u) << 16);
}

// ---------------- prep: fp32 -> bf16 conversion ----------------
__global__ void k_cvt(const float* __restrict__ src, unsigned short* __restrict__ dst, int n4) {
  int stride = gridDim.x * blockDim.x;
  for (int i = blockIdx.x * blockDim.x + threadIdx.x; i < n4; i += stride) {
    float4 v = reinterpret_cast<const float4*>(src)[i];
    ushort4 o;
    o.x = f2bf(v.x); o.y = f2bf(v.y); o.z = f2bf(v.z); o.w = f2bf(v.w);
    reinterpret_cast<ushort4*>(dst)[i] = o;
  }
}

__global__ void k_bias(const float* __restrict__ a, const float* __restrict__ b,
                       float* __restrict__ o, int n) {
  int i = blockIdx.x * blockDim.x + threadIdx.x;
  if (i < n) o[i] = a[i] + b[i];
}

// ---------------- xp GEMM: writes per-column interleaved xp layout ----------------
// out element for (row r, gate col c): r*4096 + jc*4 + gate   (jc = c&1023, gate = c>>10)
__global__ __launch_bounds__(256) void k_gemm(
    const unsigned short* __restrict__ A,
    const unsigned short* __restrict__ W,
    const float* __restrict__ bias,
    unsigned short* __restrict__ out,
    int mode) {
  const int tid = threadIdx.x, l = tid & 63, wv = tid >> 6;
  const int wm = wv >> 1, wn = wv & 1;
  const int tm = blockIdx.x >> 5, tn = blockIdx.x & 31;   // 256 x 32 tiles of 128x128
  const int m_base = tm * 128 + wm * 64;
  const int n_base = tn * 128 + wn * 64;
  const int lr = l & 15, k8 = (l >> 4) << 3;

  size_t a_off[4], b_off[4];
#pragma unroll
  for (int i = 0; i < 4; ++i) {
    int r = m_base + i * 16 + lr;
    int ar = mode ? r : (((r & 63) << 9) + (r >> 6));
    a_off[i] = ((size_t)ar << 10) + k8;
    int nr = n_base + i * 16 + lr;
    b_off[i] = ((size_t)nr << 10) + k8;
  }
  f32x4 acc[4][4] = {};
#pragma unroll 2
  for (int k0 = 0; k0 < 1024; k0 += 32) {
    short8 a[4], b[4];
#pragma unroll
    for (int i = 0; i < 4; ++i) a[i] = *reinterpret_cast<const short8*>(A + a_off[i] + k0);
#pragma unroll
    for (int j = 0; j < 4; ++j) b[j] = *reinterpret_cast<const short8*>(W + b_off[j] + k0);
#pragma unroll
    for (int i = 0; i < 4; ++i)
#pragma unroll
      for (int j = 0; j < 4; ++j) acc[i][j] = MFMA16(a[i], b[j], acc[i][j]);
  }
  const int oq = (l >> 4) << 2, oc = l & 15;
#pragma unroll
  for (int j = 0; j < 4; ++j) {
    int col = n_base + j * 16 + oc;
    int gate = col >> 10, jc = col & 1023;
    size_t cidx = (size_t)((jc << 2) + gate);
    float bs = bias[col];
#pragma unroll
    for (int i = 0; i < 4; ++i) {
      int r0 = m_base + i * 16 + oq;
#pragma unroll
      for (int q = 0; q < 4; ++q)
        out[(((size_t)(r0 + q)) << 12) + cidx] = f2bf(acc[i][j][q] + bs);
    }
  }
}

// ---------------- persistent LSTM recurrence ----------------
// grid = 128 WGs x 512 threads (1 WG/CU). Group g = wg>>5: batches [16g,16g+16).
// WG w (0..31) owns h-cols [32w, 32w+32) -> 128 gate cols.
// Wave ks (0..7): K-slice [128ks, 128ks+128). W_hh frags register-resident:
// bf[8][4] = 128 VGPR (spill-safe: 8 waves @ 1 WG/CU = 2 waves/SIMD -> 256 cap,
// enforced by __launch_bounds__(512,2)). Broadcast = 128 WGs x 32 KB = 4 MB/step.
// 2 syncthreads/step + all-waves flag poll (no trailing sync).
__global__ __launch_bounds__(512, 2) void k_rec(
    const unsigned short* __restrict__ xp,     // col-interleaved (S*B, 4096) bf16
    const unsigned short* __restrict__ Whh,    // (4096, 1024) bf16
    unsigned short* __restrict__ hbuf,         // 2 x (64 x 1024) bf16
    int* __restrict__ flags,                   // per group at +g*256: 32 flags
    unsigned short* __restrict__ out_bf,       // layer0: (S,B,1024) bf16, else null
    float* __restrict__ out_f32,               // layer1: (B,S,1024) fp32, else null
    float* __restrict__ hn, float* __restrict__ cn) {
  __shared__ float part[8 * 16 * 128];         // [ks][batch][n] 64 KB, single-buffered

  const int tid = threadIdx.x;
  const int l = tid & 63, ks = tid >> 6;       // 8 waves = 8 K-slices
  const int g = blockIdx.x >> 5;
  const int w = blockIdx.x & 31;
  const int hc0 = w << 5;

  int* gflags = flags + (g << 8);

  const int lr16 = l & 15, k8 = (l >> 4) << 3;

  // ---- W_hh fragments -> registers (once): bf[nn][kk]
  // tile col c_wg = nn*16 + lr16 (0..127); gate = c_wg>>5; local col = c_wg&31
  // W row = gate*1024 + hc0 + (c_wg&31); K = ks*128 + kk*32 + k8
  short8 bf[8][4];
#pragma unroll
  for (int nn = 0; nn < 8; ++nn) {
    const int c_wg = (nn << 4) + lr16;
    const unsigned short* wp =
        Whh + ((size_t)(((c_wg >> 5) << 10) + hc0 + (c_wg & 31)) << 10) + (ks << 7) + k8;
#pragma unroll
    for (int kk = 0; kk < 4; ++kk)
      bf[nn][kk] = *reinterpret_cast<const short8*>(wp + (kk << 5));
  }

  // a-frag base offset (within one h buffer), in ushorts
  const int arow = (g << 4) + lr16;            // batch row
  const size_t aoff = ((size_t)arow << 10) + (ks << 7) + k8;

  // elementwise mapping: all 512 threads, one (batch, hcol) each
  const int b_l = tid >> 5;                    // 0..15
  const int j = tid & 31;                      // 0..31
  const int b_g = (g << 4) + b_l;
  const int hcol = hc0 + j;

  float cs = 0.f;

  auto xload = [&](int t) -> uint2 {
    return *reinterpret_cast<const uint2*>(
        xp + (((size_t)((t << 6) + b_g)) << 12) + (hcol << 2));
  };

  auto step = [&](int t, uint2 xv) {
    if (t > 0) {
      const unsigned short* ab = hbuf + ((size_t)(t & 1) << 16) + aoff;
      short8 av[4];
#pragma unroll
      for (int kk = 0; kk < 4; ++kk) {
        const unsigned short* p = ab + (kk << 5);
        asm volatile("global_load_dwordx4 %0, %1, off sc0 sc1"
                     : "=v"(av[kk]) : "v"(p) : "memory");
      }
      asm volatile("s_waitcnt vmcnt(0)" ::: "memory");
      __builtin_amdgcn_sched_barrier(0);
      f32x4 acc[8] = {{0.f,0.f,0.f,0.f},{0.f,0.f,0.f,0.f},{0.f,0.f,0.f,0.f},{0.f,0.f,0.f,0.f},
                      {0.f,0.f,0.f,0.f},{0.f,0.f,0.f,0.f},{0.f,0.f,0.f,0.f},{0.f,0.f,0.f,0.f}};
#pragma unroll
      for (int kk = 0; kk < 4; ++kk)
#pragma unroll
        for (int nn = 0; nn < 8; ++nn)
          acc[nn] = MFMA16(av[kk], bf[nn][kk], acc[nn]);
      // D: row=(l>>4)*4+q (batch), col=lr16 within tile nn
#pragma unroll
      for (int nn = 0; nn < 8; ++nn)
#pragma unroll
        for (int q = 0; q < 4; ++q) {
          int bq = ((l >> 4) << 2) + q;
          part[(((ks << 4) + bq) << 7) + (nn << 4) + lr16] = acc[nn][q];
        }
    }
    __syncthreads();

    // ---- elementwise: one (batch, hcol) per thread
    {
      float gi = bf2f((unsigned short)(xv.x)), gf = bf2f((unsigned short)(xv.x >> 16));
      float gg = bf2f((unsigned short)(xv.y)), go = bf2f((unsigned short)(xv.y >> 16));
      if (t > 0) {
        float si = 0.f, sf = 0.f, sg = 0.f, so = 0.f;
#pragma unroll
        for (int ksx = 0; ksx < 8; ++ksx) {
          const float* p = part + (((ksx << 4) + b_l) << 7) + j;
          si += p[0];    // gate i: n = 0*32+j
          sf += p[32];   // gate f
          sg += p[64];   // gate g
          so += p[96];   // gate o
        }
        gi += si; gf += sf; gg += sg; go += so;
      }
      float iv = 1.f / (1.f + __expf(-gi));
      float fv = 1.f / (1.f + __expf(-gf));
      float gv = tanhf(gg);
      float ov = 1.f / (1.f + __expf(-go));
      cs = fv * cs + iv * gv;
      float hv = ov * tanhf(cs);
      unsigned short h16 = f2bf(hv);

      AS(hbuf + ((size_t)((t + 1) & 1) << 16) + ((size_t)b_g << 10) + hcol, h16);
      if (out_bf) {
        out_bf[((((size_t)t << 6) + b_g) << 10) + hcol] = h16;
      } else {
        out_f32[((((size_t)b_g << 9) + t) << 10) + hcol] = hv;
      }
      if (t == 511) {
        hn[((size_t)b_g << 10) + hcol] = hv;
        cn[((size_t)b_g << 10) + hcol] = cs;
      }
    }

    // ---- group barrier: drain stores, sync, arrive, ALL waves poll 32 flags ----
    if (t != 511) {
      asm volatile("s_waitcnt vmcnt(0)" ::: "memory");
      __syncthreads();
      if (tid == 0) AS(&gflags[w], t + 1);
      for (;;) {
        int f = (l < 32) ? AL(&gflags[l]) : 0x7fffffff;
        if (__all(f > t)) break;
        __builtin_amdgcn_s_sleep(1);
      }
      // no trailing syncthreads: part[] reuse is protected by the two syncs above
    }
  };

  // ---- main loop: 8-step superchunks, xp double-buffer prefetch ----
  uint2 zz = {0u, 0u};
  uint2 xA[4] = {zz, zz, zz, zz}, xB[4] = {zz, zz, zz, zz};
#pragma unroll
  for (int s = 0; s < 4; ++s) xA[s] = xload(s);
  for (int tc = 0; tc < 512; tc += 8) {
#pragma unroll
    for (int s = 0; s < 4; ++s) xB[s] = xload(tc + 4 + s);
#pragma unroll
    for (int s = 0; s < 4; ++s) step(tc + s, xA[s]);
    if (tc + 8 < 512) {
#pragma unroll
      for (int s = 0; s < 4; ++s) xA[s] = xload(tc + 8 + s);
    }
#pragma unroll
    for (int s = 0; s < 4; ++s) step(tc + 4 + s, xB[s]);
  }
}

// ---------------- launch ----------------
extern "C" void kernel_launch(void* const* d_in, const int* in_sizes, int n_in,
                              void* d_out, int out_size, void* d_ws, size_t ws_size,
                              hipStream_t stream) {
  (void)in_sizes; (void)n_in; (void)out_size; (void)ws_size;
  const float* x    = (const float*)d_in[0];
  const float* Wih0 = (const float*)d_in[1];
  const float* bih0 = (const float*)d_in[2];
  const float* Whh0 = (const float*)d_in[3];
  const float* bhh0 = (const float*)d_in[4];
  const float* Wih1 = (const float*)d_in[5];
  const float* bih1 = (const float*)d_in[6];
  const float* Whh1 = (const float*)d_in[7];
  const float* bhh1 = (const float*)d_in[8];
  float* dout = (float*)d_out;

  char* ws = (char*)d_ws;
  int*            flags = (int*)ws;                          // 8 KB
  unsigned short* hbuf  = (unsigned short*)(ws + 8192);      // 256 KB
  float*          bias0 = (float*)(ws + 270336);             // 16 KB
  float*          bias1 = (float*)(ws + 286720);             // 16 KB
  unsigned short* wbf   = (unsigned short*)(ws + 303104);    // 32 MB: ih0,hh0,ih1,hh1
  unsigned short* xbf   = wbf + 16777216;                    // 64 MB
  unsigned short* out0  = xbf + 33554432;                    // 64 MB
  unsigned short* xpb   = out0 + 33554432;                   // 256 MB (shared both layers)

  hipMemsetAsync(flags, 0, 8192, stream);

  k_cvt<<<1024, 256, 0, stream>>>(x, xbf, 33554432 / 4);
  k_cvt<<<256, 256, 0, stream>>>(Wih0, wbf + 0,        4194304 / 4);
  k_cvt<<<256, 256, 0, stream>>>(Whh0, wbf + 4194304,  4194304 / 4);
  k_cvt<<<256, 256, 0, stream>>>(Wih1, wbf + 8388608,  4194304 / 4);
  k_cvt<<<256, 256, 0, stream>>>(Whh1, wbf + 12582912, 4194304 / 4);
  k_bias<<<16, 256, 0, stream>>>(bih0, bhh0, bias0, 4096);
  k_bias<<<16, 256, 0, stream>>>(bih1, bhh1, bias1, 4096);

  float* hn = dout + 33554432;
  float* cn = dout + 33554432 + 131072;

  // layer 0
  k_gemm<<<8192, 256, 0, stream>>>(xbf, wbf + 0, bias0, xpb, 0);
  k_rec<<<128, 512, 0, stream>>>(xpb, wbf + 4194304, hbuf, flags,
                                 out0, nullptr, hn, cn);
  // layer 1
  k_gemm<<<8192, 256, 0, stream>>>(out0, wbf + 8388608, bias1, xpb, 1);
  k_rec<<<128, 512, 0, stream>>>(xpb, wbf + 12582912, hbuf, flags + 1024,
                                 nullptr, dout, hn + 65536, cn + 65536);
}

// Round 7
// 5987.782 us; speedup vs baseline: 1.9983x; 1.0226x over previous
//
#include <hip/hip_runtime.h>
#include <stdint.h>

typedef __attribute__((ext_vector_type(8))) short short8;
typedef __attribute__((ext_vector_type(4))) float f32x4;

#define MFMA16(a, b, c) __builtin_amdgcn_mfma_f32_16x16x32_bf16((a), (b), (c), 0, 0, 0)
#define AL(p) __hip_atomic_load((p), __ATOMIC_RELAXED, __HIP_MEMORY_SCOPE_AGENT)
#define AS(p, v) __hip_atomic_store((p), (v), __ATOMIC_RELAXED, __HIP_MEMORY_SCOPE_AGENT)

__device__ __forceinline__ unsigned short f2bf(float f) {
  unsigned u = __float_as_uint(f);
  u = (u + 0x7FFFu + ((u >> 16) & 1u)) >> 16;   // RNE
  return (unsigned short)u;
}
__device__ __forceinline__ float bf2f(unsigned short u) {
  return __uint_as_float(((unsigned)u) << 16);
}

// ---------------- prep: fp32 -> bf16 conversion ----------------
__global__ void k_cvt(const float* __restrict__ src, unsigned short* __restrict__ dst, int n4) {
  int stride = gridDim.x * blockDim.x;
  for (int i = blockIdx.x * blockDim.x + threadIdx.x; i < n4; i += stride) {
    float4 v = reinterpret_cast<const float4*>(src)[i];
    ushort4 o;
    o.x = f2bf(v.x); o.y = f2bf(v.y); o.z = f2bf(v.z); o.w = f2bf(v.w);
    reinterpret_cast<ushort4*>(dst)[i] = o;
  }
}

__global__ void k_bias(const float* __restrict__ a, const float* __restrict__ b,
                       float* __restrict__ o, int n) {
  int i = blockIdx.x * blockDim.x + threadIdx.x;
  if (i < n) o[i] = a[i] + b[i];
}

// ---------------- xp GEMM: writes per-column interleaved xp layout ----------------
// out element for (row r, gate col c): r*4096 + jc*4 + gate   (jc = c&1023, gate = c>>10)
__global__ __launch_bounds__(256) void k_gemm(
    const unsigned short* __restrict__ A,
    const unsigned short* __restrict__ W,
    const float* __restrict__ bias,
    unsigned short* __restrict__ out,
    int mode) {
  const int tid = threadIdx.x, l = tid & 63, wv = tid >> 6;
  const int wm = wv >> 1, wn = wv & 1;
  const int tm = blockIdx.x >> 5, tn = blockIdx.x & 31;   // 256 x 32 tiles of 128x128
  const int m_base = tm * 128 + wm * 64;
  const int n_base = tn * 128 + wn * 64;
  const int lr = l & 15, k8 = (l >> 4) << 3;

  size_t a_off[4], b_off[4];
#pragma unroll
  for (int i = 0; i < 4; ++i) {
    int r = m_base + i * 16 + lr;
    int ar = mode ? r : (((r & 63) << 9) + (r >> 6));
    a_off[i] = ((size_t)ar << 10) + k8;
    int nr = n_base + i * 16 + lr;
    b_off[i] = ((size_t)nr << 10) + k8;
  }
  f32x4 acc[4][4] = {};
#pragma unroll 2
  for (int k0 = 0; k0 < 1024; k0 += 32) {
    short8 a[4], b[4];
#pragma unroll
    for (int i = 0; i < 4; ++i) a[i] = *reinterpret_cast<const short8*>(A + a_off[i] + k0);
#pragma unroll
    for (int j = 0; j < 4; ++j) b[j] = *reinterpret_cast<const short8*>(W + b_off[j] + k0);
#pragma unroll
    for (int i = 0; i < 4; ++i)
#pragma unroll
      for (int j = 0; j < 4; ++j) acc[i][j] = MFMA16(a[i], b[j], acc[i][j]);
  }
  const int oq = (l >> 4) << 2, oc = l & 15;
#pragma unroll
  for (int j = 0; j < 4; ++j) {
    int col = n_base + j * 16 + oc;
    int gate = col >> 10, jc = col & 1023;
    size_t cidx = (size_t)((jc << 2) + gate);
    float bs = bias[col];
#pragma unroll
    for (int i = 0; i < 4; ++i) {
      int r0 = m_base + i * 16 + oq;
#pragma unroll
      for (int q = 0; q < 4; ++q)
        out[(((size_t)(r0 + q)) << 12) + cidx] = f2bf(acc[i][j][q] + bs);
    }
  }
}

// ---------------- persistent LSTM recurrence ----------------
// grid = 128 WGs x 512 threads (1 WG/CU). Group g = wg>>5: batches [16g,16g+16).
// WG w (0..31) owns h-cols [32w, 32w+32) -> 128 gate cols.
// Wave ks (0..7): K-slice [128ks, 128ks+128). W_hh frags register-resident
// (bf[8][4] = 128 VGPR, safe at 2 waves/SIMD -> 256 cap).
// Latency pack (R7): (1) wave ks polls ONLY its 4 producer WGs (4ks..4ks+3);
// (2) h store -> drain -> sync -> arrive, THEN out stores in the poll shadow.
__global__ __launch_bounds__(512, 2) void k_rec(
    const unsigned short* __restrict__ xp,     // col-interleaved (S*B, 4096) bf16
    const unsigned short* __restrict__ Whh,    // (4096, 1024) bf16
    unsigned short* __restrict__ hbuf,         // 2 x (64 x 1024) bf16
    int* __restrict__ flags,                   // per group at +g*256: 32 flags
    unsigned short* __restrict__ out_bf,       // layer0: (S,B,1024) bf16, else null
    float* __restrict__ out_f32,               // layer1: (B,S,1024) fp32, else null
    float* __restrict__ hn, float* __restrict__ cn) {
  __shared__ float part[8 * 16 * 128];         // [ks][batch][n] 64 KB, single-buffered

  const int tid = threadIdx.x;
  const int l = tid & 63, ks = tid >> 6;       // 8 waves = 8 K-slices
  const int g = blockIdx.x >> 5;
  const int w = blockIdx.x & 31;
  const int hc0 = w << 5;

  int* gflags = flags + (g << 8);

  const int lr16 = l & 15, k8 = (l >> 4) << 3;

  // ---- W_hh fragments -> registers (once): bf[nn][kk]
  short8 bf[8][4];
#pragma unroll
  for (int nn = 0; nn < 8; ++nn) {
    const int c_wg = (nn << 4) + lr16;
    const unsigned short* wp =
        Whh + ((size_t)(((c_wg >> 5) << 10) + hc0 + (c_wg & 31)) << 10) + (ks << 7) + k8;
#pragma unroll
    for (int kk = 0; kk < 4; ++kk)
      bf[nn][kk] = *reinterpret_cast<const short8*>(wp + (kk << 5));
  }

  // a-frag base offset (within one h buffer), in ushorts
  const int arow = (g << 4) + lr16;            // batch row
  const size_t aoff = ((size_t)arow << 10) + (ks << 7) + k8;

  // elementwise mapping: all 512 threads, one (batch, hcol) each
  const int b_l = tid >> 5;                    // 0..15
  const int j = tid & 31;                      // 0..31
  const int b_g = (g << 4) + b_l;
  const int hcol = hc0 + j;

  float cs = 0.f;

  auto xload = [&](int t) -> uint2 {
    return *reinterpret_cast<const uint2*>(
        xp + (((size_t)((t << 6) + b_g)) << 12) + (hcol << 2));
  };

  auto step = [&](int t, uint2 xv) {
    if (t > 0) {
      const unsigned short* ab = hbuf + ((size_t)(t & 1) << 16) + aoff;
      short8 av[4];
#pragma unroll
      for (int kk = 0; kk < 4; ++kk) {
        const unsigned short* p = ab + (kk << 5);
        asm volatile("global_load_dwordx4 %0, %1, off sc0 sc1"
                     : "=v"(av[kk]) : "v"(p) : "memory");
      }
      asm volatile("s_waitcnt vmcnt(0)" ::: "memory");
      __builtin_amdgcn_sched_barrier(0);
      f32x4 acc[8] = {{0.f,0.f,0.f,0.f},{0.f,0.f,0.f,0.f},{0.f,0.f,0.f,0.f},{0.f,0.f,0.f,0.f},
                      {0.f,0.f,0.f,0.f},{0.f,0.f,0.f,0.f},{0.f,0.f,0.f,0.f},{0.f,0.f,0.f,0.f}};
#pragma unroll
      for (int kk = 0; kk < 4; ++kk)
#pragma unroll
        for (int nn = 0; nn < 8; ++nn)
          acc[nn] = MFMA16(av[kk], bf[nn][kk], acc[nn]);
#pragma unroll
      for (int nn = 0; nn < 8; ++nn)
#pragma unroll
        for (int q = 0; q < 4; ++q) {
          int bq = ((l >> 4) << 2) + q;
          part[(((ks << 4) + bq) << 7) + (nn << 4) + lr16] = acc[nn][q];
        }
    }
    __syncthreads();   // sync1: parts visible to elementwise

    // ---- elementwise: one (batch, hcol) per thread; h store ONLY, then drain
    float hv, h1v_cs;  // kept for post-flag stores
    unsigned short h16;
    {
      float gi = bf2f((unsigned short)(xv.x)), gf = bf2f((unsigned short)(xv.x >> 16));
      float gg = bf2f((unsigned short)(xv.y)), go = bf2f((unsigned short)(xv.y >> 16));
      if (t > 0) {
        float si = 0.f, sf = 0.f, sg = 0.f, so = 0.f;
#pragma unroll
        for (int ksx = 0; ksx < 8; ++ksx) {
          const float* p = part + (((ksx << 4) + b_l) << 7) + j;
          si += p[0];
          sf += p[32];
          sg += p[64];
          so += p[96];
        }
        gi += si; gf += sf; gg += sg; go += so;
      }
      float iv = 1.f / (1.f + __expf(-gi));
      float fv = 1.f / (1.f + __expf(-gf));
      float gv = tanhf(gg);
      float ov = 1.f / (1.f + __expf(-go));
      cs = fv * cs + iv * gv;
      hv = ov * tanhf(cs);
      h1v_cs = cs;
      h16 = f2bf(hv);

      AS(hbuf + ((size_t)((t + 1) & 1) << 16) + ((size_t)b_g << 10) + hcol, h16);
    }
    asm volatile("s_waitcnt vmcnt(0)" ::: "memory");
    __syncthreads();   // sync2: all h stores drained; part[] reads done
    if (tid == 0) AS(&gflags[w], t + 1);

    // ---- out stores fire in the poll shadow (nobody consumes them this step)
    if (out_bf) {
      out_bf[((((size_t)t << 6) + b_g) << 10) + hcol] = h16;
    } else {
      out_f32[((((size_t)b_g << 9) + t) << 10) + hcol] = hv;
    }
    if (t == 511) {
      hn[((size_t)b_g << 10) + hcol] = hv;
      cn[((size_t)b_g << 10) + hcol] = h1v_cs;
    } else {
      // ---- producer-targeted poll: wave ks needs WGs 4ks..4ks+3 only
      const int base = ks << 2;
      for (;;) {
        int f = (l < 4) ? AL(&gflags[base + l]) : 0x7fffffff;
        if (__all(f > t)) break;
        __builtin_amdgcn_s_sleep(1);
      }
    }
  };

  // ---- main loop: 8-step superchunks, xp double-buffer prefetch ----
  uint2 zz = {0u, 0u};
  uint2 xA[4] = {zz, zz, zz, zz}, xB[4] = {zz, zz, zz, zz};
#pragma unroll
  for (int s = 0; s < 4; ++s) xA[s] = xload(s);
  for (int tc = 0; tc < 512; tc += 8) {
#pragma unroll
    for (int s = 0; s < 4; ++s) xB[s] = xload(tc + 4 + s);
#pragma unroll
    for (int s = 0; s < 4; ++s) step(tc + s, xA[s]);
    if (tc + 8 < 512) {
#pragma unroll
      for (int s = 0; s < 4; ++s) xA[s] = xload(tc + 8 + s);
    }
#pragma unroll
    for (int s = 0; s < 4; ++s) step(tc + 4 + s, xB[s]);
  }
}

// ---------------- launch ----------------
extern "C" void kernel_launch(void* const* d_in, const int* in_sizes, int n_in,
                              void* d_out, int out_size, void* d_ws, size_t ws_size,
                              hipStream_t stream) {
  (void)in_sizes; (void)n_in; (void)out_size; (void)ws_size;
  const float* x    = (const float*)d_in[0];
  const float* Wih0 = (const float*)d_in[1];
  const float* bih0 = (const float*)d_in[2];
  const float* Whh0 = (const float*)d_in[3];
  const float* bhh0 = (const float*)d_in[4];
  const float* Wih1 = (const float*)d_in[5];
  const float* bih1 = (const float*)d_in[6];
  const float* Whh1 = (const float*)d_in[7];
  const float* bhh1 = (const float*)d_in[8];
  float* dout = (float*)d_out;

  char* ws = (char*)d_ws;
  int*            flags = (int*)ws;                          // 8 KB
  unsigned short* hbuf  = (unsigned short*)(ws + 8192);      // 256 KB
  float*          bias0 = (float*)(ws + 270336);             // 16 KB
  float*          bias1 = (float*)(ws + 286720);             // 16 KB
  unsigned short* wbf   = (unsigned short*)(ws + 303104);    // 32 MB: ih0,hh0,ih1,hh1
  unsigned short* xbf   = wbf + 16777216;                    // 64 MB
  unsigned short* out0  = xbf + 33554432;                    // 64 MB
  unsigned short* xpb   = out0 + 33554432;                   // 256 MB (shared both layers)

  hipMemsetAsync(flags, 0, 8192, stream);

  k_cvt<<<1024, 256, 0, stream>>>(x, xbf, 33554432 / 4);
  k_cvt<<<256, 256, 0, stream>>>(Wih0, wbf + 0,        4194304 / 4);
  k_cvt<<<256, 256, 0, stream>>>(Whh0, wbf + 4194304,  4194304 / 4);
  k_cvt<<<256, 256, 0, stream>>>(Wih1, wbf + 8388608,  4194304 / 4);
  k_cvt<<<256, 256, 0, stream>>>(Whh1, wbf + 12582912, 4194304 / 4);
  k_bias<<<16, 256, 0, stream>>>(bih0, bhh0, bias0, 4096);
  k_bias<<<16, 256, 0, stream>>>(bih1, bhh1, bias1, 4096);

  float* hn = dout + 33554432;
  float* cn = dout + 33554432 + 131072;

  // layer 0
  k_gemm<<<8192, 256, 0, stream>>>(xbf, wbf + 0, bias0, xpb, 0);
  k_rec<<<128, 512, 0, stream>>>(xpb, wbf + 4194304, hbuf, flags,
                                 out0, nullptr, hn, cn);
  // layer 1
  k_gemm<<<8192, 256, 0, stream>>>(out0, wbf + 8388608, bias1, xpb, 1);
  k_rec<<<128, 512, 0, stream>>>(xpb, wbf + 12582912, hbuf, flags + 1024,
                                 nullptr, dout, hn + 65536, cn + 65536);
}

// Round 8
// 5592.552 us; speedup vs baseline: 2.1395x; 1.0707x over previous
//
#include <hip/hip_runtime.h>
#include <stdint.h>

typedef __attribute__((ext_vector_type(8))) short short8;
typedef __attribute__((ext_vector_type(4))) float f32x4;

#define MFMA16(a, b, c) __builtin_amdgcn_mfma_f32_16x16x32_bf16((a), (b), (c), 0, 0, 0)
#define AL(p) __hip_atomic_load((p), __ATOMIC_RELAXED, __HIP_MEMORY_SCOPE_AGENT)
#define AS(p, v) __hip_atomic_store((p), (v), __ATOMIC_RELAXED, __HIP_MEMORY_SCOPE_AGENT)

__device__ __forceinline__ unsigned short f2bf(float f) {
  unsigned u = __float_as_uint(f);
  u = (u + 0x7FFFu + ((u >> 16) & 1u)) >> 16;   // RNE
  return (unsigned short)u;
}
__device__ __forceinline__ float bf2f(unsigned short u) {
  return __uint_as_float(((unsigned)u) << 16);
}

// ---------------- prep ----------------
__global__ void k_cvt(const float* __restrict__ src, unsigned short* __restrict__ dst, int n4) {
  int stride = gridDim.x * blockDim.x;
  for (int i = blockIdx.x * blockDim.x + threadIdx.x; i < n4; i += stride) {
    float4 v = reinterpret_cast<const float4*>(src)[i];
    ushort4 o;
    o.x = f2bf(v.x); o.y = f2bf(v.y); o.z = f2bf(v.z); o.w = f2bf(v.w);
    reinterpret_cast<ushort4*>(dst)[i] = o;
  }
}

__global__ void k_cvtw(const float* s0, const float* s1, const float* s2, const float* s3,
                       unsigned short* __restrict__ dst) {
  int i = blockIdx.x * blockDim.x + threadIdx.x;
  if (i >= 4194304) return;
  const float* srcs[4] = {s0, s1, s2, s3};
  const float* sp = srcs[i >> 20];
  float4 v = reinterpret_cast<const float4*>(sp)[i & 1048575];
  ushort4 o;
  o.x = f2bf(v.x); o.y = f2bf(v.y); o.z = f2bf(v.z); o.w = f2bf(v.w);
  reinterpret_cast<ushort4*>(dst)[i] = o;
}

__global__ void k_bias2(const float* a0, const float* b0, const float* a1, const float* b1,
                        float* __restrict__ o0, float* __restrict__ o1) {
  int i = blockIdx.x * blockDim.x + threadIdx.x;
  if (i < 4096) { o0[i] = a0[i] + b0[i]; o1[i] = a1[i] + b1[i]; }
}

// ---------------- xp GEMM (layer0): per-column interleaved xp layout ----------------
// out element for (row r, gate col c): r*4096 + jc*4 + gate   (jc = c&1023, gate = c>>10)
__global__ __launch_bounds__(256) void k_gemm(
    const unsigned short* __restrict__ A,
    const unsigned short* __restrict__ W,
    const float* __restrict__ bias,
    unsigned short* __restrict__ out,
    int mode) {
  const int tid = threadIdx.x, l = tid & 63, wv = tid >> 6;
  const int wm = wv >> 1, wn = wv & 1;
  const int tm = blockIdx.x >> 5, tn = blockIdx.x & 31;
  const int m_base = tm * 128 + wm * 64;
  const int n_base = tn * 128 + wn * 64;
  const int lr = l & 15, k8 = (l >> 4) << 3;

  size_t a_off[4], b_off[4];
#pragma unroll
  for (int i = 0; i < 4; ++i) {
    int r = m_base + i * 16 + lr;
    int ar = mode ? r : (((r & 63) << 9) + (r >> 6));
    a_off[i] = ((size_t)ar << 10) + k8;
    int nr = n_base + i * 16 + lr;
    b_off[i] = ((size_t)nr << 10) + k8;
  }
  f32x4 acc[4][4] = {};
#pragma unroll 2
  for (int k0 = 0; k0 < 1024; k0 += 32) {
    short8 a[4], b[4];
#pragma unroll
    for (int i = 0; i < 4; ++i) a[i] = *reinterpret_cast<const short8*>(A + a_off[i] + k0);
#pragma unroll
    for (int j = 0; j < 4; ++j) b[j] = *reinterpret_cast<const short8*>(W + b_off[j] + k0);
#pragma unroll
    for (int i = 0; i < 4; ++i)
#pragma unroll
      for (int j = 0; j < 4; ++j) acc[i][j] = MFMA16(a[i], b[j], acc[i][j]);
  }
  const int oq = (l >> 4) << 2, oc = l & 15;
#pragma unroll
  for (int j = 0; j < 4; ++j) {
    int col = n_base + j * 16 + oc;
    int gate = col >> 10, jc = col & 1023;
    size_t cidx = (size_t)((jc << 2) + gate);
    float bs = bias[col];
#pragma unroll
    for (int i = 0; i < 4; ++i) {
      int r0 = m_base + i * 16 + oq;
#pragma unroll
      for (int q = 0; q < 4; ++q)
        out[(((size_t)(r0 + q)) << 12) + cidx] = f2bf(acc[i][j][q] + bs);
    }
  }
}

// ---------------- persistent LSTM recurrence body (R7 structure) ----------------
// 128 WGs x 512 thr. Group g = wg>>5: batches [16g,16g+16). WG w: h-cols [32w,32w+32).
// Wave ks: K-slice. W_hh register-resident. out_bf stores are sc1 (AS) so the
// overlapped gemm consumer can read them; sentinel flag 1000 after the loop.
__device__ __forceinline__ void rec_body(
    const unsigned short* __restrict__ xp,
    const unsigned short* __restrict__ Whh,
    unsigned short* __restrict__ hbuf,
    int* __restrict__ flags,
    unsigned short* __restrict__ out_bf,
    float* __restrict__ out_f32,
    float* __restrict__ hn, float* __restrict__ cn,
    float* part, int wg) {
  const int tid = threadIdx.x;
  const int l = tid & 63, ks = tid >> 6;
  const int g = wg >> 5;
  const int w = wg & 31;
  const int hc0 = w << 5;

  int* gflags = flags + (g << 8);
  const int lr16 = l & 15, k8 = (l >> 4) << 3;

  short8 bf[8][4];
#pragma unroll
  for (int nn = 0; nn < 8; ++nn) {
    const int c_wg = (nn << 4) + lr16;
    const unsigned short* wp =
        Whh + ((size_t)(((c_wg >> 5) << 10) + hc0 + (c_wg & 31)) << 10) + (ks << 7) + k8;
#pragma unroll
    for (int kk = 0; kk < 4; ++kk)
      bf[nn][kk] = *reinterpret_cast<const short8*>(wp + (kk << 5));
  }

  const int arow = (g << 4) + lr16;
  const size_t aoff = ((size_t)arow << 10) + (ks << 7) + k8;

  const int b_l = tid >> 5;
  const int j = tid & 31;
  const int b_g = (g << 4) + b_l;
  const int hcol = hc0 + j;

  float cs = 0.f;

  auto xload = [&](int t) -> uint2 {
    return *reinterpret_cast<const uint2*>(
        xp + (((size_t)((t << 6) + b_g)) << 12) + (hcol << 2));
  };

  auto step = [&](int t, uint2 xv) {
    if (t > 0) {
      const unsigned short* ab = hbuf + ((size_t)(t & 1) << 16) + aoff;
      short8 av[4];
#pragma unroll
      for (int kk = 0; kk < 4; ++kk) {
        const unsigned short* p = ab + (kk << 5);
        asm volatile("global_load_dwordx4 %0, %1, off sc0 sc1"
                     : "=v"(av[kk]) : "v"(p) : "memory");
      }
      asm volatile("s_waitcnt vmcnt(0)" ::: "memory");
      __builtin_amdgcn_sched_barrier(0);
      f32x4 acc[8] = {{0.f,0.f,0.f,0.f},{0.f,0.f,0.f,0.f},{0.f,0.f,0.f,0.f},{0.f,0.f,0.f,0.f},
                      {0.f,0.f,0.f,0.f},{0.f,0.f,0.f,0.f},{0.f,0.f,0.f,0.f},{0.f,0.f,0.f,0.f}};
#pragma unroll
      for (int kk = 0; kk < 4; ++kk)
#pragma unroll
        for (int nn = 0; nn < 8; ++nn)
          acc[nn] = MFMA16(av[kk], bf[nn][kk], acc[nn]);
#pragma unroll
      for (int nn = 0; nn < 8; ++nn)
#pragma unroll
        for (int q = 0; q < 4; ++q) {
          int bq = ((l >> 4) << 2) + q;
          part[(((ks << 4) + bq) << 7) + (nn << 4) + lr16] = acc[nn][q];
        }
    }
    __syncthreads();

    float hv, cv;
    unsigned short h16;
    {
      float gi = bf2f((unsigned short)(xv.x)), gf = bf2f((unsigned short)(xv.x >> 16));
      float gg = bf2f((unsigned short)(xv.y)), go = bf2f((unsigned short)(xv.y >> 16));
      if (t > 0) {
        float si = 0.f, sf = 0.f, sg = 0.f, so = 0.f;
#pragma unroll
        for (int ksx = 0; ksx < 8; ++ksx) {
          const float* p = part + (((ksx << 4) + b_l) << 7) + j;
          si += p[0];
          sf += p[32];
          sg += p[64];
          so += p[96];
        }
        gi += si; gf += sf; gg += sg; go += so;
      }
      float iv = 1.f / (1.f + __expf(-gi));
      float fv = 1.f / (1.f + __expf(-gf));
      float gv = tanhf(gg);
      float ov = 1.f / (1.f + __expf(-go));
      cs = fv * cs + iv * gv;
      hv = ov * tanhf(cs);
      cv = cs;
      h16 = f2bf(hv);
      AS(hbuf + ((size_t)((t + 1) & 1) << 16) + ((size_t)b_g << 10) + hcol, h16);
    }
    asm volatile("s_waitcnt vmcnt(0)" ::: "memory");
    __syncthreads();
    if (tid == 0) AS(&gflags[w], t + 1);

    // out stores in the poll shadow (sc1 for out_bf: gemm consumer reads via MALL)
    if (out_bf) {
      AS(out_bf + ((((size_t)t << 6) + b_g) << 10) + hcol, h16);
    } else {
      out_f32[((((size_t)b_g << 9) + t) << 10) + hcol] = hv;
    }
    if (t == 511) {
      hn[((size_t)b_g << 10) + hcol] = hv;
      cn[((size_t)b_g << 10) + hcol] = cv;
    } else {
      const int base = ks << 2;
      for (;;) {
        int f = (l < 4) ? AL(&gflags[base + l]) : 0x7fffffff;
        if (__all(f > t)) break;
        __builtin_amdgcn_s_sleep(1);
      }
    }
  };

  uint2 zz = {0u, 0u};
  uint2 xA[4] = {zz, zz, zz, zz}, xB[4] = {zz, zz, zz, zz};
#pragma unroll
  for (int s = 0; s < 4; ++s) xA[s] = xload(s);
  for (int tc = 0; tc < 512; tc += 8) {
#pragma unroll
    for (int s = 0; s < 4; ++s) xB[s] = xload(tc + 4 + s);
#pragma unroll
    for (int s = 0; s < 4; ++s) step(tc + s, xA[s]);
    if (tc + 8 < 512) {
#pragma unroll
      for (int s = 0; s < 4; ++s) xA[s] = xload(tc + 8 + s);
    }
#pragma unroll
    for (int s = 0; s < 4; ++s) step(tc + 4 + s, xB[s]);
  }

  // sentinel: certifies all stores (incl. out[511]) drained
  asm volatile("s_waitcnt vmcnt(0)" ::: "memory");
  __syncthreads();
  if (tid == 0) AS(&gflags[w], 1000);
}

__global__ __launch_bounds__(512, 2) void k_rec(
    const unsigned short* __restrict__ xp,
    const unsigned short* __restrict__ Whh,
    unsigned short* __restrict__ hbuf,
    int* __restrict__ flags,
    unsigned short* __restrict__ out_bf,
    float* __restrict__ out_f32,
    float* __restrict__ hn, float* __restrict__ cn) {
  __shared__ float part[8 * 16 * 128];
  rec_body(xp, Whh, hbuf, flags, out_bf, out_f32, hn, cn, part, blockIdx.x);
}

// ---------------- gemm1 consumer side (runs on WGs 128..255 of k_fused) ----------------
// Chunk c (64 timesteps) computed after rec0 group flags >= 64(c+1)+1.
// A = out0 rows (sc1, staged to XOR-swizzled LDS), B = W_ih1 (plain, L2-hot).
// Writes xpb rows of the chunk in place (rec0 already consumed them).
__device__ __forceinline__ void gemm_side(
    const unsigned short* __restrict__ A,
    const unsigned short* __restrict__ W,
    const float* __restrict__ bias,
    unsigned short* __restrict__ out,
    int* __restrict__ flags, char* smem, int gw) {
  const int tid = threadIdx.x, l = tid & 63, wv = tid >> 6;
  const int wm = wv >> 2, wn = wv & 3;
  const int g = gw >> 5, u = gw & 31;
  const int tshi = u >> 4, ng = u & 15;
  const int lr16 = l & 15, k8 = (l >> 4) << 3;
  int* gfl = flags + (g << 8);

  for (int c = 0; c < 8; ++c) {
    const int thr = (c < 7) ? (((c + 1) << 6) + 1) : 1000;
    for (;;) {
      int f = (l < 32) ? AL(&gfl[l]) : 0x7fffffff;
      if (__all(f >= thr)) break;
      __builtin_amdgcn_s_sleep(8);
    }
    for (int tsl = 0; tsl < 4; ++tsl) {
      const int ts = (tshi << 2) + tsl;
      f32x4 acc[2][4][2] = {};
      for (int kh = 0; kh < 2; ++kh) {
        // ---- stage A half-tile (128 rows x 512 K) into swizzled LDS
        short8 st[16];
#pragma unroll
        for (int s = 0; s < 16; ++s) {
          int ch = tid + (s << 9);
          int i = ch >> 6, c16 = ch & 63;
          int t = (c << 6) + (ts << 3) + (i >> 4);
          int b = (g << 4) + (i & 15);
          const unsigned short* p =
              A + (((size_t)((t << 6) + b)) << 10) + (kh << 9) + (c16 << 3);
          asm volatile("global_load_dwordx4 %0, %1, off sc0 sc1"
                       : "=v"(st[s]) : "v"(p) : "memory");
        }
        asm volatile("s_waitcnt vmcnt(0)" ::: "memory");
        __builtin_amdgcn_sched_barrier(0);
#pragma unroll
        for (int s = 0; s < 16; ++s) {
          int ch = tid + (s << 9);
          int i = ch >> 6, c16 = ch & 63;
          *reinterpret_cast<short8*>(smem + (i << 10) + ((c16 ^ (i & 7)) << 4)) = st[s];
        }
        __syncthreads();
        // ---- MFMA over the half-tile
        for (int nn = 0; nn < 2; ++nn) {
          const int ncol0 = (((ng << 1) + nn) << 7) + (wn << 5);
#pragma unroll
          for (int kk = 0; kk < 16; ++kk) {
            short8 a[4], bfr[2];
            int c16 = ((kk << 5) + k8) >> 3;
#pragma unroll
            for (int fi = 0; fi < 4; ++fi) {
              int row = (wm << 6) + (fi << 4) + lr16;
              a[fi] = *reinterpret_cast<const short8*>(
                  smem + (row << 10) + ((c16 ^ (row & 7)) << 4));
            }
#pragma unroll
            for (int jj = 0; jj < 2; ++jj) {
              int col = ncol0 + (jj << 4) + lr16;
              bfr[jj] = *reinterpret_cast<const short8*>(
                  W + ((size_t)col << 10) + (kh << 9) + (kk << 5) + k8);
            }
#pragma unroll
            for (int fi = 0; fi < 4; ++fi)
#pragma unroll
              for (int jj = 0; jj < 2; ++jj)
                acc[nn][fi][jj] = MFMA16(a[fi], bfr[jj], acc[nn][fi][jj]);
          }
        }
        __syncthreads();
      }
      // ---- epilogue for this m-tile (interleaved xp layout + bias)
      const int oq = (l >> 4) << 2, oc = l & 15;
#pragma unroll
      for (int nn = 0; nn < 2; ++nn)
#pragma unroll
        for (int jj = 0; jj < 2; ++jj) {
          int col = (((ng << 1) + nn) << 7) + (wn << 5) + (jj << 4) + oc;
          int gate = col >> 10, jc = col & 1023;
          size_t cidx = (size_t)((jc << 2) + gate);
          float bs = bias[col];
#pragma unroll
          for (int fi = 0; fi < 4; ++fi) {
            int t = (c << 6) + (ts << 3) + (wm << 2) + fi;
#pragma unroll
            for (int q = 0; q < 4; ++q) {
              int b = (g << 4) + oq + q;
              out[(((size_t)((t << 6) + b)) << 12) + cidx] = f2bf(acc[nn][fi][jj][q] + bs);
            }
          }
        }
    }
  }
}

// ---------------- fused: rec0 (WGs 0..127)  ||  chunked gemm1 (WGs 128..255) ----------------
__global__ __launch_bounds__(512, 2) void k_fused(
    const unsigned short* __restrict__ xp0,
    const unsigned short* __restrict__ Whh0,
    unsigned short* __restrict__ hbuf,
    int* __restrict__ flags,
    unsigned short* __restrict__ out0,
    float* __restrict__ hn, float* __restrict__ cn,
    const unsigned short* __restrict__ Wih1,
    const float* __restrict__ bias1,
    unsigned short* __restrict__ xpb) {
  extern __shared__ char smem[];
  if (blockIdx.x < 128) {
    rec_body(xp0, Whh0, hbuf, flags, out0, nullptr, hn, cn, (float*)smem, blockIdx.x);
  } else {
    gemm_side(out0, Wih1, bias1, xpb, flags, smem, blockIdx.x - 128);
  }
}

// ---------------- launch ----------------
extern "C" void kernel_launch(void* const* d_in, const int* in_sizes, int n_in,
                              void* d_out, int out_size, void* d_ws, size_t ws_size,
                              hipStream_t stream) {
  (void)in_sizes; (void)n_in; (void)out_size; (void)ws_size;
  const float* x    = (const float*)d_in[0];
  const float* Wih0 = (const float*)d_in[1];
  const float* bih0 = (const float*)d_in[2];
  const float* Whh0 = (const float*)d_in[3];
  const float* bhh0 = (const float*)d_in[4];
  const float* Wih1 = (const float*)d_in[5];
  const float* bih1 = (const float*)d_in[6];
  const float* Whh1 = (const float*)d_in[7];
  const float* bhh1 = (const float*)d_in[8];
  float* dout = (float*)d_out;

  char* ws = (char*)d_ws;
  int*            flags = (int*)ws;                          // 8 KB
  unsigned short* hbuf  = (unsigned short*)(ws + 8192);      // 256 KB
  float*          bias0 = (float*)(ws + 270336);             // 16 KB
  float*          bias1 = (float*)(ws + 286720);             // 16 KB
  unsigned short* wbf   = (unsigned short*)(ws + 303104);    // 32 MB: ih0,hh0,ih1,hh1
  unsigned short* xbf   = wbf + 16777216;                    // 64 MB
  unsigned short* out0  = xbf + 33554432;                    // 64 MB
  unsigned short* xpb   = out0 + 33554432;                   // 256 MB (shared: xp0 then xp1 in place)

  hipMemsetAsync(flags, 0, 8192, stream);

  k_cvt<<<1024, 256, 0, stream>>>(x, xbf, 33554432 / 4);
  k_cvtw<<<16384, 256, 0, stream>>>(Wih0, Whh0, Wih1, Whh1, wbf);
  k_bias2<<<16, 256, 0, stream>>>(bih0, bhh0, bih1, bhh1, bias0, bias1);

  float* hn = dout + 33554432;
  float* cn = dout + 33554432 + 131072;

  // layer 0 xp
  k_gemm<<<8192, 256, 0, stream>>>(xbf, wbf + 0, bias0, xpb, 0);

  // fused: rec0 || chunked gemm1 (xp1 overwrites xpb in place behind rec0's flags)
  hipFuncSetAttribute((const void*)k_fused,
                      hipFuncAttributeMaxDynamicSharedMemorySize, 131072);
  k_fused<<<256, 512, 131072, stream>>>(xpb, wbf + 4194304, hbuf, flags,
                                        out0, hn, cn,
                                        wbf + 8388608, bias1, xpb);

  // layer 1 recurrence
  k_rec<<<128, 512, 0, stream>>>(xpb, wbf + 12582912, hbuf, flags + 1024,
                                 nullptr, dout, hn + 65536, cn + 65536);
}

// Round 9
// 4728.861 us; speedup vs baseline: 2.5303x; 1.1826x over previous
//
#include <hip/hip_runtime.h>
#include <stdint.h>

typedef __attribute__((ext_vector_type(8))) short short8;
typedef __attribute__((ext_vector_type(4))) float f32x4;

#define MFMA16(a, b, c) __builtin_amdgcn_mfma_f32_16x16x32_bf16((a), (b), (c), 0, 0, 0)
#define AL(p) __hip_atomic_load((p), __ATOMIC_RELAXED, __HIP_MEMORY_SCOPE_AGENT)
#define AS(p, v) __hip_atomic_store((p), (v), __ATOMIC_RELAXED, __HIP_MEMORY_SCOPE_AGENT)

__device__ __forceinline__ unsigned short f2bf(float f) {
  unsigned u = __float_as_uint(f);
  u = (u + 0x7FFFu + ((u >> 16) & 1u)) >> 16;   // RNE
  return (unsigned short)u;
}
__device__ __forceinline__ float bf2f(unsigned short u) {
  return __uint_as_float(((unsigned)u) << 16);
}

// ---------------- prep ----------------
__global__ void k_cvt(const float* __restrict__ src, unsigned short* __restrict__ dst, int n4) {
  int stride = gridDim.x * blockDim.x;
  for (int i = blockIdx.x * blockDim.x + threadIdx.x; i < n4; i += stride) {
    float4 v = reinterpret_cast<const float4*>(src)[i];
    ushort4 o;
    o.x = f2bf(v.x); o.y = f2bf(v.y); o.z = f2bf(v.z); o.w = f2bf(v.w);
    reinterpret_cast<ushort4*>(dst)[i] = o;
  }
}

__global__ void k_cvtw(const float* s0, const float* s1, const float* s2, const float* s3,
                       unsigned short* __restrict__ dst) {
  int i = blockIdx.x * blockDim.x + threadIdx.x;
  if (i >= 4194304) return;
  const float* srcs[4] = {s0, s1, s2, s3};
  const float* sp = srcs[i >> 20];
  float4 v = reinterpret_cast<const float4*>(sp)[i & 1048575];
  ushort4 o;
  o.x = f2bf(v.x); o.y = f2bf(v.y); o.z = f2bf(v.z); o.w = f2bf(v.w);
  reinterpret_cast<ushort4*>(dst)[i] = o;
}

__global__ void k_bias2(const float* a0, const float* b0, const float* a1, const float* b1,
                        float* __restrict__ o0, float* __restrict__ o1) {
  int i = blockIdx.x * blockDim.x + threadIdx.x;
  if (i < 4096) { o0[i] = a0[i] + b0[i]; o1[i] = a1[i] + b1[i]; }
}

// ---------------- xp GEMM (layer0): per-column interleaved xp layout ----------------
__global__ __launch_bounds__(256) void k_gemm(
    const unsigned short* __restrict__ A,
    const unsigned short* __restrict__ W,
    const float* __restrict__ bias,
    unsigned short* __restrict__ out,
    int mode) {
  const int tid = threadIdx.x, l = tid & 63, wv = tid >> 6;
  const int wm = wv >> 1, wn = wv & 1;
  const int tm = blockIdx.x >> 5, tn = blockIdx.x & 31;
  const int m_base = tm * 128 + wm * 64;
  const int n_base = tn * 128 + wn * 64;
  const int lr = l & 15, k8 = (l >> 4) << 3;

  size_t a_off[4], b_off[4];
#pragma unroll
  for (int i = 0; i < 4; ++i) {
    int r = m_base + i * 16 + lr;
    int ar = mode ? r : (((r & 63) << 9) + (r >> 6));
    a_off[i] = ((size_t)ar << 10) + k8;
    int nr = n_base + i * 16 + lr;
    b_off[i] = ((size_t)nr << 10) + k8;
  }
  f32x4 acc[4][4] = {};
#pragma unroll 2
  for (int k0 = 0; k0 < 1024; k0 += 32) {
    short8 a[4], b[4];
#pragma unroll
    for (int i = 0; i < 4; ++i) a[i] = *reinterpret_cast<const short8*>(A + a_off[i] + k0);
#pragma unroll
    for (int j = 0; j < 4; ++j) b[j] = *reinterpret_cast<const short8*>(W + b_off[j] + k0);
#pragma unroll
    for (int i = 0; i < 4; ++i)
#pragma unroll
      for (int j = 0; j < 4; ++j) acc[i][j] = MFMA16(a[i], b[j], acc[i][j]);
  }
  const int oq = (l >> 4) << 2, oc = l & 15;
#pragma unroll
  for (int j = 0; j < 4; ++j) {
    int col = n_base + j * 16 + oc;
    int gate = col >> 10, jc = col & 1023;
    size_t cidx = (size_t)((jc << 2) + gate);
    float bs = bias[col];
#pragma unroll
    for (int i = 0; i < 4; ++i) {
      int r0 = m_base + i * 16 + oq;
#pragma unroll
      for (int q = 0; q < 4; ++q)
        out[(((size_t)(r0 + q)) << 12) + cidx] = f2bf(acc[i][j][q] + bs);
    }
  }
}

// ---------------- layer-0 recurrence (R8 proven structure) ----------------
__device__ __forceinline__ void rec0_body(
    const unsigned short* __restrict__ xp,
    const unsigned short* __restrict__ Whh,
    unsigned short* __restrict__ hbuf,
    int* __restrict__ gflags,
    unsigned short* __restrict__ out_bf,
    float* __restrict__ hn, float* __restrict__ cn,
    float* part, int w, int g) {
  const int tid = threadIdx.x;
  const int l = tid & 63, ks = tid >> 6;
  const int hc0 = w << 5;
  const int lr16 = l & 15, k8 = (l >> 4) << 3;

  short8 bf[8][4];
#pragma unroll
  for (int nn = 0; nn < 8; ++nn) {
    const int c_wg = (nn << 4) + lr16;
    const unsigned short* wp =
        Whh + ((size_t)(((c_wg >> 5) << 10) + hc0 + (c_wg & 31)) << 10) + (ks << 7) + k8;
#pragma unroll
    for (int kk = 0; kk < 4; ++kk)
      bf[nn][kk] = *reinterpret_cast<const short8*>(wp + (kk << 5));
  }

  const int arow = (g << 4) + lr16;
  const size_t aoff = ((size_t)arow << 10) + (ks << 7) + k8;

  const int b_l = tid >> 5;
  const int j = tid & 31;
  const int b_g = (g << 4) + b_l;
  const int hcol = hc0 + j;

  float cs = 0.f;

  auto xload = [&](int t) -> uint2 {
    return *reinterpret_cast<const uint2*>(
        xp + (((size_t)((t << 6) + b_g)) << 12) + (hcol << 2));
  };

  auto step = [&](int t, uint2 xv) {
    if (t > 0) {
      const unsigned short* ab = hbuf + ((size_t)(t & 1) << 16) + aoff;
      short8 av[4];
#pragma unroll
      for (int kk = 0; kk < 4; ++kk) {
        const unsigned short* p = ab + (kk << 5);
        asm volatile("global_load_dwordx4 %0, %1, off sc0 sc1"
                     : "=v"(av[kk]) : "v"(p) : "memory");
      }
      asm volatile("s_waitcnt vmcnt(0)" ::: "memory");
      __builtin_amdgcn_sched_barrier(0);
      f32x4 acc[8] = {{0.f,0.f,0.f,0.f},{0.f,0.f,0.f,0.f},{0.f,0.f,0.f,0.f},{0.f,0.f,0.f,0.f},
                      {0.f,0.f,0.f,0.f},{0.f,0.f,0.f,0.f},{0.f,0.f,0.f,0.f},{0.f,0.f,0.f,0.f}};
#pragma unroll
      for (int kk = 0; kk < 4; ++kk)
#pragma unroll
        for (int nn = 0; nn < 8; ++nn)
          acc[nn] = MFMA16(av[kk], bf[nn][kk], acc[nn]);
#pragma unroll
      for (int nn = 0; nn < 8; ++nn)
#pragma unroll
        for (int q = 0; q < 4; ++q) {
          int bq = ((l >> 4) << 2) + q;
          part[(((ks << 4) + bq) << 7) + (nn << 4) + lr16] = acc[nn][q];
        }
    }
    __syncthreads();

    float hv, cv;
    unsigned short h16;
    {
      float gi = bf2f((unsigned short)(xv.x)), gf = bf2f((unsigned short)(xv.x >> 16));
      float gg = bf2f((unsigned short)(xv.y)), go = bf2f((unsigned short)(xv.y >> 16));
      if (t > 0) {
        float si = 0.f, sf = 0.f, sg = 0.f, so = 0.f;
#pragma unroll
        for (int ksx = 0; ksx < 8; ++ksx) {
          const float* p = part + (((ksx << 4) + b_l) << 7) + j;
          si += p[0]; sf += p[32]; sg += p[64]; so += p[96];
        }
        gi += si; gf += sf; gg += sg; go += so;
      }
      float iv = 1.f / (1.f + __expf(-gi));
      float fv = 1.f / (1.f + __expf(-gf));
      float gv = tanhf(gg);
      float ov = 1.f / (1.f + __expf(-go));
      cs = fv * cs + iv * gv;
      hv = ov * tanhf(cs);
      cv = cs;
      h16 = f2bf(hv);
      AS(hbuf + ((size_t)((t + 1) & 1) << 16) + ((size_t)b_g << 10) + hcol, h16);
    }
    asm volatile("s_waitcnt vmcnt(0)" ::: "memory");
    __syncthreads();
    if (tid == 0) AS(&gflags[w], t + 1);

    AS(out_bf + ((((size_t)t << 6) + b_g) << 10) + hcol, h16);
    if (t == 511) {
      hn[((size_t)b_g << 10) + hcol] = hv;
      cn[((size_t)b_g << 10) + hcol] = cv;
    } else {
      const int base = ks << 2;
      for (;;) {
        int f = (l < 4) ? AL(&gflags[base + l]) : 0x7fffffff;
        if (__all(f > t)) break;
        __builtin_amdgcn_s_sleep(1);
      }
    }
  };

  uint2 zz = {0u, 0u};
  uint2 xA[4] = {zz, zz, zz, zz}, xB[4] = {zz, zz, zz, zz};
#pragma unroll
  for (int s = 0; s < 4; ++s) xA[s] = xload(s);
  for (int tc = 0; tc < 512; tc += 8) {
#pragma unroll
    for (int s = 0; s < 4; ++s) xB[s] = xload(tc + 4 + s);
#pragma unroll
    for (int s = 0; s < 4; ++s) step(tc + s, xA[s]);
    if (tc + 8 < 512) {
#pragma unroll
      for (int s = 0; s < 4; ++s) xA[s] = xload(tc + 8 + s);
    }
#pragma unroll
    for (int s = 0; s < 4; ++s) step(tc + 4 + s, xB[s]);
  }

  asm volatile("s_waitcnt vmcnt(0)" ::: "memory");
  __syncthreads();
  if (tid == 0) AS(&gflags[w], 1000);
}

// ---------------- layer-1: per-chunk {own-col gemm -> private xpp; 64 rec steps} ----------
__device__ __forceinline__ void layer1_body(
    const unsigned short* __restrict__ out0,
    const unsigned short* __restrict__ Wih1,
    const float* __restrict__ bias1,
    const unsigned short* __restrict__ Whh1,
    unsigned short* __restrict__ xpp,      // private 256 KB (131072 ushorts)
    unsigned short* __restrict__ hbuf,     // layer-1 h ring (2 x 128 KB)
    int* __restrict__ gflags0,
    int* __restrict__ gflags1,
    float* __restrict__ outf,
    float* __restrict__ hn, float* __restrict__ cn,
    float* part, int u, int g) {
  const int tid = threadIdx.x;
  const int l = tid & 63, ks = tid >> 6;
  const int hc0 = u << 5;
  const int lr16 = l & 15, k8 = (l >> 4) << 3;

  // W_hh1 fragments -> registers (as rec0)
  short8 bf[8][4];
#pragma unroll
  for (int nn = 0; nn < 8; ++nn) {
    const int c_wg = (nn << 4) + lr16;
    const unsigned short* wp =
        Whh1 + ((size_t)(((c_wg >> 5) << 10) + hc0 + (c_wg & 31)) << 10) + (ks << 7) + k8;
#pragma unroll
    for (int kk = 0; kk < 4; ++kk)
      bf[nn][kk] = *reinterpret_cast<const short8*>(wp + (kk << 5));
  }

  const int arow = (g << 4) + lr16;
  const size_t aoff = ((size_t)arow << 10) + (ks << 7) + k8;

  const int b_l = tid >> 5;
  const int j = tid & 31;
  const int b_g = (g << 4) + b_l;
  const int hcol = hc0 + j;

  // gemm constants: wave ks = n-tile (16 of our 128 cols)
  const int cg = (ks << 4) + lr16;            // 0..127
  const int gate = cg >> 5, jl = cg & 31;
  const int wrow = (gate << 10) + hc0 + jl;   // W_ih1 row == bias index
  const float bsv = bias1[wrow];
  char* smem = (char*)part;

  float cs = 0.f;

  for (int c = 0; c < 8; ++c) {
    // ---- gate on rec0: out0 rows of chunk c certified ----
    const int thr = (c < 7) ? (((c + 1) << 6) + 1) : 1000;
    for (;;) {
      int f = (l < 32) ? AL(&gflags0[l]) : 0x7fffffff;
      if (__all(f >= thr)) break;
      __builtin_amdgcn_s_sleep(8);
    }
    __syncthreads();

    // ---- gemm: xp1 chunk (64 t x 16 b x our 128 gate cols), K=1024 ----
    for (int mb = 0; mb < 16; ++mb) {
      f32x4 acc[4] = {{0.f,0.f,0.f,0.f},{0.f,0.f,0.f,0.f},{0.f,0.f,0.f,0.f},{0.f,0.f,0.f,0.f}};
#pragma unroll 1
      for (int kh = 0; kh < 2; ++kh) {
        // stage A: 64 rows (4 ti x 16 b) x 512 K -> 64 KB swizzled LDS
        short8 st[8];
#pragma unroll
        for (int s = 0; s < 8; ++s) {
          int ch = tid + (s << 9);
          int row = ch >> 6, kc = ch & 63;
          int t = (c << 6) + (mb << 2) + (row >> 4);
          int b = (g << 4) + (row & 15);
          const unsigned short* p =
              out0 + (((size_t)((t << 6) + b)) << 10) + (kh << 9) + (kc << 3);
          asm volatile("global_load_dwordx4 %0, %1, off sc0 sc1"
                       : "=v"(st[s]) : "v"(p) : "memory");
        }
        asm volatile("s_waitcnt vmcnt(0)" ::: "memory");
        __builtin_amdgcn_sched_barrier(0);
#pragma unroll
        for (int s = 0; s < 8; ++s) {
          int ch = tid + (s << 9);
          int row = ch >> 6, kc = ch & 63;
          *reinterpret_cast<short8*>(smem + (row << 10) + ((kc ^ (row & 7)) << 4)) = st[s];
        }
        __syncthreads();
#pragma unroll
        for (int kk = 0; kk < 16; ++kk) {
          short8 bfr = *reinterpret_cast<const short8*>(
              Wih1 + ((size_t)wrow << 10) + (kh << 9) + (kk << 5) + k8);
          int kc = (kk << 2) + (k8 >> 3);
#pragma unroll
          for (int mt = 0; mt < 4; ++mt) {
            int row = (mt << 4) + lr16;
            short8 a = *reinterpret_cast<const short8*>(
                smem + (row << 10) + ((kc ^ (row & 7)) << 4));
            acc[mt] = MFMA16(a, bfr, acc[mt]);
          }
        }
        __syncthreads();
      }
      // epilogue -> private xpp (plain cached stores; own WG reads back)
#pragma unroll
      for (int mt = 0; mt < 4; ++mt) {
        int ti = (mb << 2) + mt;
#pragma unroll
        for (int q = 0; q < 4; ++q) {
          int bi = ((l >> 4) << 2) + q;
          xpp[(((ti << 4) + bi) << 7) + (jl << 2) + gate] = f2bf(acc[mt][q] + bsv);
        }
      }
    }
    asm volatile("s_waitcnt vmcnt(0)" ::: "memory");
    __syncthreads();   // xpp visible WG-wide

    // ---- 64 recurrent steps ----
    for (int ti = 0; ti < 64; ++ti) {
      const int t = (c << 6) + ti;
      uint2 xv = *reinterpret_cast<const uint2*>(xpp + (((ti << 4) + b_l) << 7) + (j << 2));

      if (t > 0) {
        const unsigned short* ab = hbuf + ((size_t)(t & 1) << 16) + aoff;
        short8 av[4];
#pragma unroll
        for (int kk = 0; kk < 4; ++kk) {
          const unsigned short* p = ab + (kk << 5);
          asm volatile("global_load_dwordx4 %0, %1, off sc0 sc1"
                       : "=v"(av[kk]) : "v"(p) : "memory");
        }
        asm volatile("s_waitcnt vmcnt(0)" ::: "memory");
        __builtin_amdgcn_sched_barrier(0);
        f32x4 acc[8] = {{0.f,0.f,0.f,0.f},{0.f,0.f,0.f,0.f},{0.f,0.f,0.f,0.f},{0.f,0.f,0.f,0.f},
                        {0.f,0.f,0.f,0.f},{0.f,0.f,0.f,0.f},{0.f,0.f,0.f,0.f},{0.f,0.f,0.f,0.f}};
#pragma unroll
        for (int kk = 0; kk < 4; ++kk)
#pragma unroll
          for (int nn = 0; nn < 8; ++nn)
            acc[nn] = MFMA16(av[kk], bf[nn][kk], acc[nn]);
#pragma unroll
        for (int nn = 0; nn < 8; ++nn)
#pragma unroll
          for (int q = 0; q < 4; ++q) {
            int bq = ((l >> 4) << 2) + q;
            part[(((ks << 4) + bq) << 7) + (nn << 4) + lr16] = acc[nn][q];
          }
      }
      __syncthreads();

      float hv, cv;
      unsigned short h16;
      {
        float gi = bf2f((unsigned short)(xv.x)), gf = bf2f((unsigned short)(xv.x >> 16));
        float gg = bf2f((unsigned short)(xv.y)), go = bf2f((unsigned short)(xv.y >> 16));
        if (t > 0) {
          float si = 0.f, sf = 0.f, sg = 0.f, so = 0.f;
#pragma unroll
          for (int ksx = 0; ksx < 8; ++ksx) {
            const float* p = part + (((ksx << 4) + b_l) << 7) + j;
            si += p[0]; sf += p[32]; sg += p[64]; so += p[96];
          }
          gi += si; gf += sf; gg += sg; go += so;
        }
        float iv = 1.f / (1.f + __expf(-gi));
        float fv = 1.f / (1.f + __expf(-gf));
        float gv = tanhf(gg);
        float ov = 1.f / (1.f + __expf(-go));
        cs = fv * cs + iv * gv;
        hv = ov * tanhf(cs);
        cv = cs;
        h16 = f2bf(hv);
        AS(hbuf + ((size_t)((t + 1) & 1) << 16) + ((size_t)b_g << 10) + hcol, h16);
      }
      asm volatile("s_waitcnt vmcnt(0)" ::: "memory");
      __syncthreads();
      if (tid == 0) AS(&gflags1[u], t + 1);

      outf[((((size_t)b_g << 9) + t) << 10) + hcol] = hv;
      if (t == 511) {
        hn[((size_t)b_g << 10) + hcol] = hv;
        cn[((size_t)b_g << 10) + hcol] = cv;
      } else {
        const int base = ks << 2;
        for (;;) {
          int f = (l < 4) ? AL(&gflags1[base + l]) : 0x7fffffff;
          if (__all(f > t)) break;
          __builtin_amdgcn_s_sleep(1);
        }
      }
    }
  }
}

// ---------------- fused: rec0 (WGs 0..127) || gemm1+rec1 pipeline (WGs 128..255) ------
__global__ __launch_bounds__(512, 2) void k_fused(
    const unsigned short* __restrict__ xp0,
    const unsigned short* __restrict__ Whh0,
    unsigned short* __restrict__ hb0,
    int* __restrict__ flags0,
    unsigned short* __restrict__ out0,
    float* __restrict__ hn, float* __restrict__ cn,
    const unsigned short* __restrict__ Wih1,
    const float* __restrict__ bias1,
    const unsigned short* __restrict__ Whh1,
    unsigned short* __restrict__ xpp_all,
    unsigned short* __restrict__ hb1,
    int* __restrict__ flags1,
    float* __restrict__ outf) {
  __shared__ float part[8 * 16 * 128];   // 64 KB, dual-purpose
  const int wg = blockIdx.x;
  if (wg < 128) {
    rec0_body(xp0, Whh0, hb0, flags0 + ((wg >> 5) << 8), out0, hn, cn,
              part, wg & 31, wg >> 5);
  } else {
    const int wg1 = wg - 128;
    layer1_body(out0, Wih1, bias1, Whh1,
                xpp_all + ((size_t)wg1 << 17),
                hb1, flags0 + ((wg1 >> 5) << 8), flags1 + ((wg1 >> 5) << 8),
                outf, hn + 65536, cn + 65536,
                part, wg1 & 31, wg1 >> 5);
  }
}

// ---------------- launch ----------------
extern "C" void kernel_launch(void* const* d_in, const int* in_sizes, int n_in,
                              void* d_out, int out_size, void* d_ws, size_t ws_size,
                              hipStream_t stream) {
  (void)in_sizes; (void)n_in; (void)out_size; (void)ws_size;
  const float* x    = (const float*)d_in[0];
  const float* Wih0 = (const float*)d_in[1];
  const float* bih0 = (const float*)d_in[2];
  const float* Whh0 = (const float*)d_in[3];
  const float* bhh0 = (const float*)d_in[4];
  const float* Wih1 = (const float*)d_in[5];
  const float* bih1 = (const float*)d_in[6];
  const float* Whh1 = (const float*)d_in[7];
  const float* bhh1 = (const float*)d_in[8];
  float* dout = (float*)d_out;

  char* ws = (char*)d_ws;
  int*            flags0 = (int*)ws;                         // 4 KB (4 groups x 256)
  int*            flags1 = (int*)(ws + 4096);                // 4 KB
  unsigned short* hb0    = (unsigned short*)(ws + 8192);     // 256 KB
  unsigned short* hb1    = (unsigned short*)(ws + 270336);   // 256 KB
  float*          bias0  = (float*)(ws + 532480);            // 16 KB
  float*          bias1  = (float*)(ws + 548864);            // 16 KB
  unsigned short* wbf    = (unsigned short*)(ws + 565248);   // 32 MB: ih0,hh0,ih1,hh1
  unsigned short* xbf    = wbf + 16777216;                   // 64 MB (x bf16; reused as xpp)
  unsigned short* out0   = xbf + 33554432;                   // 64 MB
  unsigned short* xpb    = out0 + 33554432;                  // 256 MB (xp0)

  hipMemsetAsync(flags0, 0, 8192, stream);

  k_cvt<<<1024, 256, 0, stream>>>(x, xbf, 33554432 / 4);
  k_cvtw<<<16384, 256, 0, stream>>>(Wih0, Whh0, Wih1, Whh1, wbf);
  k_bias2<<<16, 256, 0, stream>>>(bih0, bhh0, bih1, bhh1, bias0, bias1);

  float* hn = dout + 33554432;
  float* cn = dout + 33554432 + 131072;

  // layer 0 xp (must complete before k_fused: stream order)
  k_gemm<<<8192, 256, 0, stream>>>(xbf, wbf + 0, bias0, xpb, 0);

  // fused two-layer pipeline (xbf dead after gemm0 -> reused as private xpp)
  k_fused<<<256, 512, 0, stream>>>(xpb, wbf + 4194304, hb0, flags0,
                                   out0, hn, cn,
                                   wbf + 8388608, bias1, wbf + 12582912,
                                   xbf, hb1, flags1, dout);
}

// Round 10
// 4689.869 us; speedup vs baseline: 2.5513x; 1.0083x over previous
//
#include <hip/hip_runtime.h>
#include <stdint.h>

typedef __attribute__((ext_vector_type(8))) short short8;
typedef __attribute__((ext_vector_type(4))) float f32x4;

#define MFMA16(a, b, c) __builtin_amdgcn_mfma_f32_16x16x32_bf16((a), (b), (c), 0, 0, 0)
#define AL(p) __hip_atomic_load((p), __ATOMIC_RELAXED, __HIP_MEMORY_SCOPE_AGENT)
#define AS(p, v) __hip_atomic_store((p), (v), __ATOMIC_RELAXED, __HIP_MEMORY_SCOPE_AGENT)

__device__ __forceinline__ unsigned short f2bf(float f) {
  unsigned u = __float_as_uint(f);
  u = (u + 0x7FFFu + ((u >> 16) & 1u)) >> 16;   // RNE
  return (unsigned short)u;
}
__device__ __forceinline__ float bf2f(unsigned short u) {
  return __uint_as_float(((unsigned)u) << 16);
}

// ---------------- prep ----------------
__global__ void k_cvt(const float* __restrict__ src, unsigned short* __restrict__ dst, int n4) {
  int stride = gridDim.x * blockDim.x;
  for (int i = blockIdx.x * blockDim.x + threadIdx.x; i < n4; i += stride) {
    float4 v = reinterpret_cast<const float4*>(src)[i];
    ushort4 o;
    o.x = f2bf(v.x); o.y = f2bf(v.y); o.z = f2bf(v.z); o.w = f2bf(v.w);
    reinterpret_cast<ushort4*>(dst)[i] = o;
  }
}

__global__ void k_cvtw(const float* s0, const float* s1, const float* s2, const float* s3,
                       unsigned short* __restrict__ dst) {
  int i = blockIdx.x * blockDim.x + threadIdx.x;
  if (i >= 4194304) return;
  const float* srcs[4] = {s0, s1, s2, s3};
  const float* sp = srcs[i >> 20];
  float4 v = reinterpret_cast<const float4*>(sp)[i & 1048575];
  ushort4 o;
  o.x = f2bf(v.x); o.y = f2bf(v.y); o.z = f2bf(v.z); o.w = f2bf(v.w);
  reinterpret_cast<ushort4*>(dst)[i] = o;
}

__global__ void k_bias2(const float* a0, const float* b0, const float* a1, const float* b1,
                        float* __restrict__ o0, float* __restrict__ o1) {
  int i = blockIdx.x * blockDim.x + threadIdx.x;
  if (i < 4096) { o0[i] = a0[i] + b0[i]; o1[i] = a1[i] + b1[i]; }
}

// ---------------- xp GEMM (layer0): per-column interleaved xp layout ----------------
__global__ __launch_bounds__(256) void k_gemm(
    const unsigned short* __restrict__ A,
    const unsigned short* __restrict__ W,
    const float* __restrict__ bias,
    unsigned short* __restrict__ out,
    int mode) {
  const int tid = threadIdx.x, l = tid & 63, wv = tid >> 6;
  const int wm = wv >> 1, wn = wv & 1;
  const int tm = blockIdx.x >> 5, tn = blockIdx.x & 31;
  const int m_base = tm * 128 + wm * 64;
  const int n_base = tn * 128 + wn * 64;
  const int lr = l & 15, k8 = (l >> 4) << 3;

  size_t a_off[4], b_off[4];
#pragma unroll
  for (int i = 0; i < 4; ++i) {
    int r = m_base + i * 16 + lr;
    int ar = mode ? r : (((r & 63) << 9) + (r >> 6));
    a_off[i] = ((size_t)ar << 10) + k8;
    int nr = n_base + i * 16 + lr;
    b_off[i] = ((size_t)nr << 10) + k8;
  }
  f32x4 acc[4][4] = {};
#pragma unroll 2
  for (int k0 = 0; k0 < 1024; k0 += 32) {
    short8 a[4], b[4];
#pragma unroll
    for (int i = 0; i < 4; ++i) a[i] = *reinterpret_cast<const short8*>(A + a_off[i] + k0);
#pragma unroll
    for (int j = 0; j < 4; ++j) b[j] = *reinterpret_cast<const short8*>(W + b_off[j] + k0);
#pragma unroll
    for (int i = 0; i < 4; ++i)
#pragma unroll
      for (int j = 0; j < 4; ++j) acc[i][j] = MFMA16(a[i], b[j], acc[i][j]);
  }
  const int oq = (l >> 4) << 2, oc = l & 15;
#pragma unroll
  for (int j = 0; j < 4; ++j) {
    int col = n_base + j * 16 + oc;
    int gate = col >> 10, jc = col & 1023;
    size_t cidx = (size_t)((jc << 2) + gate);
    float bs = bias[col];
#pragma unroll
    for (int i = 0; i < 4; ++i) {
      int r0 = m_base + i * 16 + oq;
#pragma unroll
      for (int q = 0; q < 4; ++q)
        out[(((size_t)(r0 + q)) << 12) + cidx] = f2bf(acc[i][j][q] + bs);
    }
  }
}

// ---------------- layer-0 recurrence (R8 proven structure) ----------------
__device__ __forceinline__ void rec0_body(
    const unsigned short* __restrict__ xp,
    const unsigned short* __restrict__ Whh,
    unsigned short* __restrict__ hbuf,
    int* __restrict__ gflags,
    unsigned short* __restrict__ out_bf,
    float* __restrict__ hn, float* __restrict__ cn,
    float* part, int w, int g) {
  const int tid = threadIdx.x;
  const int l = tid & 63, ks = tid >> 6;
  const int hc0 = w << 5;
  const int lr16 = l & 15, k8 = (l >> 4) << 3;

  short8 bf[8][4];
#pragma unroll
  for (int nn = 0; nn < 8; ++nn) {
    const int c_wg = (nn << 4) + lr16;
    const unsigned short* wp =
        Whh + ((size_t)(((c_wg >> 5) << 10) + hc0 + (c_wg & 31)) << 10) + (ks << 7) + k8;
#pragma unroll
    for (int kk = 0; kk < 4; ++kk)
      bf[nn][kk] = *reinterpret_cast<const short8*>(wp + (kk << 5));
  }

  const int arow = (g << 4) + lr16;
  const size_t aoff = ((size_t)arow << 10) + (ks << 7) + k8;

  const int b_l = tid >> 5;
  const int j = tid & 31;
  const int b_g = (g << 4) + b_l;
  const int hcol = hc0 + j;

  float cs = 0.f;

  auto xload = [&](int t) -> uint2 {
    return *reinterpret_cast<const uint2*>(
        xp + (((size_t)((t << 6) + b_g)) << 12) + (hcol << 2));
  };

  auto step = [&](int t, uint2 xv) {
    if (t > 0) {
      const unsigned short* ab = hbuf + ((size_t)(t & 1) << 16) + aoff;
      short8 av[4];
#pragma unroll
      for (int kk = 0; kk < 4; ++kk) {
        const unsigned short* p = ab + (kk << 5);
        asm volatile("global_load_dwordx4 %0, %1, off sc0 sc1"
                     : "=v"(av[kk]) : "v"(p) : "memory");
      }
      asm volatile("s_waitcnt vmcnt(0)" ::: "memory");
      __builtin_amdgcn_sched_barrier(0);
      f32x4 acc[8] = {{0.f,0.f,0.f,0.f},{0.f,0.f,0.f,0.f},{0.f,0.f,0.f,0.f},{0.f,0.f,0.f,0.f},
                      {0.f,0.f,0.f,0.f},{0.f,0.f,0.f,0.f},{0.f,0.f,0.f,0.f},{0.f,0.f,0.f,0.f}};
#pragma unroll
      for (int kk = 0; kk < 4; ++kk)
#pragma unroll
        for (int nn = 0; nn < 8; ++nn)
          acc[nn] = MFMA16(av[kk], bf[nn][kk], acc[nn]);
#pragma unroll
      for (int nn = 0; nn < 8; ++nn)
#pragma unroll
        for (int q = 0; q < 4; ++q) {
          int bq = ((l >> 4) << 2) + q;
          part[(((ks << 4) + bq) << 7) + (nn << 4) + lr16] = acc[nn][q];
        }
    }
    __syncthreads();

    float hv, cv;
    unsigned short h16;
    {
      float gi = bf2f((unsigned short)(xv.x)), gf = bf2f((unsigned short)(xv.x >> 16));
      float gg = bf2f((unsigned short)(xv.y)), go = bf2f((unsigned short)(xv.y >> 16));
      if (t > 0) {
        float si = 0.f, sf = 0.f, sg = 0.f, so = 0.f;
#pragma unroll
        for (int ksx = 0; ksx < 8; ++ksx) {
          const float* p = part + (((ksx << 4) + b_l) << 7) + j;
          si += p[0]; sf += p[32]; sg += p[64]; so += p[96];
        }
        gi += si; gf += sf; gg += sg; go += so;
      }
      float iv = 1.f / (1.f + __expf(-gi));
      float fv = 1.f / (1.f + __expf(-gf));
      float gv = tanhf(gg);
      float ov = 1.f / (1.f + __expf(-go));
      cs = fv * cs + iv * gv;
      hv = ov * tanhf(cs);
      cv = cs;
      h16 = f2bf(hv);
      AS(hbuf + ((size_t)((t + 1) & 1) << 16) + ((size_t)b_g << 10) + hcol, h16);
    }
    asm volatile("s_waitcnt vmcnt(0)" ::: "memory");
    __syncthreads();
    if (tid == 0) AS(&gflags[w], t + 1);

    AS(out_bf + ((((size_t)t << 6) + b_g) << 10) + hcol, h16);
    if (t == 511) {
      hn[((size_t)b_g << 10) + hcol] = hv;
      cn[((size_t)b_g << 10) + hcol] = cv;
    } else {
      const int base = ks << 2;
      for (;;) {
        int f = (l < 4) ? AL(&gflags[base + l]) : 0x7fffffff;
        if (__all(f > t)) break;
        __builtin_amdgcn_s_sleep(1);
      }
    }
  };

  uint2 zz = {0u, 0u};
  uint2 xA[4] = {zz, zz, zz, zz}, xB[4] = {zz, zz, zz, zz};
#pragma unroll
  for (int s = 0; s < 4; ++s) xA[s] = xload(s);
  for (int tc = 0; tc < 512; tc += 8) {
#pragma unroll
    for (int s = 0; s < 4; ++s) xB[s] = xload(tc + 4 + s);
#pragma unroll
    for (int s = 0; s < 4; ++s) step(tc + s, xA[s]);
    if (tc + 8 < 512) {
#pragma unroll
      for (int s = 0; s < 4; ++s) xA[s] = xload(tc + 8 + s);
    }
#pragma unroll
    for (int s = 0; s < 4; ++s) step(tc + 4 + s, xB[s]);
  }

  asm volatile("s_waitcnt vmcnt(0)" ::: "memory");
  __syncthreads();
  if (tid == 0) AS(&gflags[w], 1000);
}

// ---------------- layer-1: per-chunk {own-col gemm -> private xpp; 64 rec steps} ----------
__device__ __forceinline__ void layer1_body(
    const unsigned short* __restrict__ out0,
    const unsigned short* __restrict__ Wih1,
    const float* __restrict__ bias1,
    const unsigned short* __restrict__ Whh1,
    unsigned short* __restrict__ xpp,      // private 256 KB (131072 ushorts)
    unsigned short* __restrict__ hbuf,     // layer-1 h ring (2 x 128 KB)
    int* __restrict__ gflags0,
    int* __restrict__ gflags1,
    float* __restrict__ outf,
    float* __restrict__ hn, float* __restrict__ cn,
    float* part, int u, int g) {
  const int tid = threadIdx.x;
  const int l = tid & 63, ks = tid >> 6;
  const int hc0 = u << 5;
  const int lr16 = l & 15, k8 = (l >> 4) << 3;

  // W_hh1 fragments -> registers (as rec0)
  short8 bf[8][4];
#pragma unroll
  for (int nn = 0; nn < 8; ++nn) {
    const int c_wg = (nn << 4) + lr16;
    const unsigned short* wp =
        Whh1 + ((size_t)(((c_wg >> 5) << 10) + hc0 + (c_wg & 31)) << 10) + (ks << 7) + k8;
#pragma unroll
    for (int kk = 0; kk < 4; ++kk)
      bf[nn][kk] = *reinterpret_cast<const short8*>(wp + (kk << 5));
  }

  const int arow = (g << 4) + lr16;
  const size_t aoff = ((size_t)arow << 10) + (ks << 7) + k8;

  const int b_l = tid >> 5;
  const int j = tid & 31;
  const int b_g = (g << 4) + b_l;
  const int hcol = hc0 + j;

  // gemm constants: wave ks = n-tile (16 of our 128 cols)
  const int cg = (ks << 4) + lr16;            // 0..127
  const int gate = cg >> 5, jl = cg & 31;
  const int wrow = (gate << 10) + hc0 + jl;   // W_ih1 row == bias index
  const float bsv = bias1[wrow];
  char* smem = (char*)part;

  float cs = 0.f;

  for (int c = 0; c < 8; ++c) {
    // ---- gate on rec0: single-lane poll (keep flag lines quiet for rec0) ----
    const int thr = (c < 7) ? (((c + 1) << 6) + 1) : 1000;
    if (tid == 0) {
      for (;;) {
        bool ok = true;
        for (int i = 0; i < 32; ++i)
          if (AL(&gflags0[i]) < thr) { ok = false; break; }
        if (ok) break;
        __builtin_amdgcn_s_sleep(16);
      }
    }
    __syncthreads();

    // ---- gemm: xp1 chunk (64 t x 16 b x our 128 gate cols), K=1024 ----
    // A loads are PLAIN cached (L2-shared across WGs of the XCD); flag order +
    // deterministic replay data make this safe.
    for (int mb = 0; mb < 16; ++mb) {
      f32x4 acc[4] = {{0.f,0.f,0.f,0.f},{0.f,0.f,0.f,0.f},{0.f,0.f,0.f,0.f},{0.f,0.f,0.f,0.f}};
#pragma unroll 1
      for (int kh = 0; kh < 2; ++kh) {
        // stage A: 64 rows (4 ti x 16 b) x 512 K -> 64 KB swizzled LDS
        short8 st[8];
#pragma unroll
        for (int s = 0; s < 8; ++s) {
          int ch = tid + (s << 9);
          int row = ch >> 6, kc = ch & 63;
          int t = (c << 6) + (mb << 2) + (row >> 4);
          int b = (g << 4) + (row & 15);
          st[s] = *reinterpret_cast<const short8*>(
              out0 + (((size_t)((t << 6) + b)) << 10) + (kh << 9) + (kc << 3));
        }
#pragma unroll
        for (int s = 0; s < 8; ++s) {
          int ch = tid + (s << 9);
          int row = ch >> 6, kc = ch & 63;
          *reinterpret_cast<short8*>(smem + (row << 10) + ((kc ^ (row & 7)) << 4)) = st[s];
        }
        __syncthreads();
#pragma unroll
        for (int kk = 0; kk < 16; ++kk) {
          short8 bfr = *reinterpret_cast<const short8*>(
              Wih1 + ((size_t)wrow << 10) + (kh << 9) + (kk << 5) + k8);
          int kc = (kk << 2) + (k8 >> 3);
#pragma unroll
          for (int mt = 0; mt < 4; ++mt) {
            int row = (mt << 4) + lr16;
            short8 a = *reinterpret_cast<const short8*>(
                smem + (row << 10) + ((kc ^ (row & 7)) << 4));
            acc[mt] = MFMA16(a, bfr, acc[mt]);
          }
        }
        __syncthreads();
      }
      // epilogue -> private xpp (plain cached stores; own WG reads back)
#pragma unroll
      for (int mt = 0; mt < 4; ++mt) {
        int ti = (mb << 2) + mt;
#pragma unroll
        for (int q = 0; q < 4; ++q) {
          int bi = ((l >> 4) << 2) + q;
          xpp[(((ti << 4) + bi) << 7) + (jl << 2) + gate] = f2bf(acc[mt][q] + bsv);
        }
      }
    }
    asm volatile("s_waitcnt vmcnt(0)" ::: "memory");
    __syncthreads();   // xpp visible WG-wide

    // ---- 64 recurrent steps ----
    for (int ti = 0; ti < 64; ++ti) {
      const int t = (c << 6) + ti;
      uint2 xv = *reinterpret_cast<const uint2*>(xpp + (((ti << 4) + b_l) << 7) + (j << 2));

      if (t > 0) {
        const unsigned short* ab = hbuf + ((size_t)(t & 1) << 16) + aoff;
        short8 av[4];
#pragma unroll
        for (int kk = 0; kk < 4; ++kk) {
          const unsigned short* p = ab + (kk << 5);
          asm volatile("global_load_dwordx4 %0, %1, off sc0 sc1"
                       : "=v"(av[kk]) : "v"(p) : "memory");
        }
        asm volatile("s_waitcnt vmcnt(0)" ::: "memory");
        __builtin_amdgcn_sched_barrier(0);
        f32x4 acc[8] = {{0.f,0.f,0.f,0.f},{0.f,0.f,0.f,0.f},{0.f,0.f,0.f,0.f},{0.f,0.f,0.f,0.f},
                        {0.f,0.f,0.f,0.f},{0.f,0.f,0.f,0.f},{0.f,0.f,0.f,0.f},{0.f,0.f,0.f,0.f}};
#pragma unroll
        for (int kk = 0; kk < 4; ++kk)
#pragma unroll
          for (int nn = 0; nn < 8; ++nn)
            acc[nn] = MFMA16(av[kk], bf[nn][kk], acc[nn]);
#pragma unroll
        for (int nn = 0; nn < 8; ++nn)
#pragma unroll
          for (int q = 0; q < 4; ++q) {
            int bq = ((l >> 4) << 2) + q;
            part[(((ks << 4) + bq) << 7) + (nn << 4) + lr16] = acc[nn][q];
          }
      }
      __syncthreads();

      float hv, cv;
      unsigned short h16;
      {
        float gi = bf2f((unsigned short)(xv.x)), gf = bf2f((unsigned short)(xv.x >> 16));
        float gg = bf2f((unsigned short)(xv.y)), go = bf2f((unsigned short)(xv.y >> 16));
        if (t > 0) {
          float si = 0.f, sf = 0.f, sg = 0.f, so = 0.f;
#pragma unroll
          for (int ksx = 0; ksx < 8; ++ksx) {
            const float* p = part + (((ksx << 4) + b_l) << 7) + j;
            si += p[0]; sf += p[32]; sg += p[64]; so += p[96];
          }
          gi += si; gf += sf; gg += sg; go += so;
        }
        float iv = 1.f / (1.f + __expf(-gi));
        float fv = 1.f / (1.f + __expf(-gf));
        float gv = tanhf(gg);
        float ov = 1.f / (1.f + __expf(-go));
        cs = fv * cs + iv * gv;
        hv = ov * tanhf(cs);
        cv = cs;
        h16 = f2bf(hv);
        AS(hbuf + ((size_t)((t + 1) & 1) << 16) + ((size_t)b_g << 10) + hcol, h16);
      }
      asm volatile("s_waitcnt vmcnt(0)" ::: "memory");
      __syncthreads();
      if (tid == 0) AS(&gflags1[u], t + 1);

      outf[((((size_t)b_g << 9) + t) << 10) + hcol] = hv;
      if (t == 511) {
        hn[((size_t)b_g << 10) + hcol] = hv;
        cn[((size_t)b_g << 10) + hcol] = cv;
      } else {
        const int base = ks << 2;
        for (;;) {
          int f = (l < 4) ? AL(&gflags1[base + l]) : 0x7fffffff;
          if (__all(f > t)) break;
          __builtin_amdgcn_s_sleep(1);
        }
      }
    }
  }
}

// ---------------- fused: rec0 (WGs 0..127) || gemm1+rec1 pipeline (WGs 128..255) ------
__global__ __launch_bounds__(512, 2) void k_fused(
    const unsigned short* __restrict__ xp0,
    const unsigned short* __restrict__ Whh0,
    unsigned short* __restrict__ hb0,
    int* __restrict__ flags0,
    unsigned short* __restrict__ out0,
    float* __restrict__ hn, float* __restrict__ cn,
    const unsigned short* __restrict__ Wih1,
    const float* __restrict__ bias1,
    const unsigned short* __restrict__ Whh1,
    unsigned short* __restrict__ xpp_all,
    unsigned short* __restrict__ hb1,
    int* __restrict__ flags1,
    float* __restrict__ outf) {
  __shared__ float part[8 * 16 * 128];   // 64 KB, dual-purpose
  const int wg = blockIdx.x;
  if (wg < 128) {
    rec0_body(xp0, Whh0, hb0, flags0 + ((wg >> 5) << 8), out0, hn, cn,
              part, wg & 31, wg >> 5);
  } else {
    const int wg1 = wg - 128;
    layer1_body(out0, Wih1, bias1, Whh1,
                xpp_all + ((size_t)wg1 << 17),
                hb1, flags0 + ((wg1 >> 5) << 8), flags1 + ((wg1 >> 5) << 8),
                outf, hn + 65536, cn + 65536,
                part, wg1 & 31, wg1 >> 5);
  }
}

// ---------------- launch ----------------
extern "C" void kernel_launch(void* const* d_in, const int* in_sizes, int n_in,
                              void* d_out, int out_size, void* d_ws, size_t ws_size,
                              hipStream_t stream) {
  (void)in_sizes; (void)n_in; (void)out_size; (void)ws_size;
  const float* x    = (const float*)d_in[0];
  const float* Wih0 = (const float*)d_in[1];
  const float* bih0 = (const float*)d_in[2];
  const float* Whh0 = (const float*)d_in[3];
  const float* bhh0 = (const float*)d_in[4];
  const float* Wih1 = (const float*)d_in[5];
  const float* bih1 = (const float*)d_in[6];
  const float* Whh1 = (const float*)d_in[7];
  const float* bhh1 = (const float*)d_in[8];
  float* dout = (float*)d_out;

  char* ws = (char*)d_ws;
  int*            flags0 = (int*)ws;                         // 4 KB (4 groups x 256)
  int*            flags1 = (int*)(ws + 4096);                // 4 KB
  unsigned short* hb0    = (unsigned short*)(ws + 8192);     // 256 KB
  unsigned short* hb1    = (unsigned short*)(ws + 270336);   // 256 KB
  float*          bias0  = (float*)(ws + 532480);            // 16 KB
  float*          bias1  = (float*)(ws + 548864);            // 16 KB
  unsigned short* wbf    = (unsigned short*)(ws + 565248);   // 32 MB: ih0,hh0,ih1,hh1
  unsigned short* xbf    = wbf + 16777216;                   // 64 MB (x bf16; reused as xpp)
  unsigned short* out0   = xbf + 33554432;                   // 64 MB
  unsigned short* xpb    = out0 + 33554432;                  // 256 MB (xp0)

  hipMemsetAsync(flags0, 0, 8192, stream);

  k_cvt<<<1024, 256, 0, stream>>>(x, xbf, 33554432 / 4);
  k_cvtw<<<16384, 256, 0, stream>>>(Wih0, Whh0, Wih1, Whh1, wbf);
  k_bias2<<<16, 256, 0, stream>>>(bih0, bhh0, bih1, bhh1, bias0, bias1);

  float* hn = dout + 33554432;
  float* cn = dout + 33554432 + 131072;

  // layer 0 xp (must complete before k_fused: stream order)
  k_gemm<<<8192, 256, 0, stream>>>(xbf, wbf + 0, bias0, xpb, 0);

  // fused two-layer pipeline (xbf dead after gemm0 -> reused as private xpp)
  k_fused<<<256, 512, 0, stream>>>(xpb, wbf + 4194304, hb0, flags0,
                                   out0, hn, cn,
                                   wbf + 8388608, bias1, wbf + 12582912,
                                   xbf, hb1, flags1, dout);
}